// Round 10
// baseline (260.835 us; speedup 1.0000x reference)
//
#include <hip/hip_runtime.h>

#define M_NODES 50000
#define E_EDGES 600000
#define SCAN_B ((M_NODES + 255) / 256)
#define B_H 64
#define EPB (E_EDGES / B_H)          // 9375
#define HWORDS (M_NODES / 2)         // 25000 packed u32 = 100 KB LDS

typedef short bf16x8 __attribute__((ext_vector_type(8)));
typedef float f32x4 __attribute__((ext_vector_type(4)));

__device__ __forceinline__ unsigned short f2bf(float f){
  unsigned u = __float_as_uint(f);
  u += 0x7FFFu + ((u >> 16) & 1u);
  return (unsigned short)(u >> 16);
}
__device__ __forceinline__ float bf2f(unsigned short h){
  return __uint_as_float(((unsigned)h) << 16);
}
__device__ __forceinline__ void gl_lds16(const void* g, void* l){
  __builtin_amdgcn_global_load_lds(
      (const __attribute__((address_space(1))) unsigned int*)g,
      (__attribute__((address_space(3))) unsigned int*)l, 16, 0, 0);
}

// ---------- fused: weight prep (split hi/lo, transposed) + activation cast (pure bf16) ----------
__global__ __launch_bounds__(256) void k_prep(
    const float* __restrict__ ws0, const float* __restrict__ wn0,
    const float* __restrict__ ws1, const float* __restrict__ wn1,
    const float* __restrict__ ws2, const float* __restrict__ wn2,
    const float* __restrict__ lw0, const float* __restrict__ lw1,
    const float* __restrict__ lw2, const float* __restrict__ H,
    unsigned short* __restrict__ W0h, unsigned short* __restrict__ W0l,
    unsigned short* __restrict__ W1h, unsigned short* __restrict__ W1l,
    unsigned short* __restrict__ W2h, unsigned short* __restrict__ W2l,
    unsigned short* __restrict__ L0h, unsigned short* __restrict__ L0l,
    unsigned short* __restrict__ L1h, unsigned short* __restrict__ L1l,
    unsigned short* __restrict__ L2h, unsigned short* __restrict__ L2l,
    char* __restrict__ X){
  const int b = blockIdx.x, t = threadIdx.x;
  if (b < 384){                      // stacked [ws;wn] -> [N=128][K=256]
    const int wsel = b >> 7;
    const int i = (b & 127)*256 + t;
    const float* Wa = wsel==0?ws0:(wsel==1?ws1:ws2);
    const float* Wb = wsel==0?wn0:(wsel==1?wn1:wn2);
    unsigned short* Th = wsel==0?W0h:(wsel==1?W1h:W2h);
    unsigned short* Tl = wsel==0?W0l:(wsel==1?W1l:W2l);
    int n = i >> 8, k = i & 255;
    float v = (k < 128) ? Wa[k*128 + n] : Wb[(k-128)*128 + n];
    unsigned short hi = f2bf(v);
    Th[n*256 + k] = hi; Tl[n*256 + k] = f2bf(v - bf2f(hi));
  } else if (b < 512){               // lw0/lw1 [128][128] -> [128][128]^T
    const int lsel = (b - 384) >> 6;
    const int i = ((b - 384) & 63)*256 + t;
    const float* W = lsel==0?lw0:lw1;
    unsigned short* Th = lsel==0?L0h:L1h;
    unsigned short* Tl = lsel==0?L0l:L1l;
    int n = i >> 7, k = i & 127;
    float v = W[k*128 + n];
    unsigned short hi = f2bf(v);
    Th[n*128 + k] = hi; Tl[n*128 + k] = f2bf(v - bf2f(hi));
  } else if (b < 544){               // lw2 [128][64] -> [64][128]^T
    const int i = (b - 512)*256 + t;
    if (i >= 64*128) return;
    int n = i >> 7, k = i & 127;
    float v = lw2[k*64 + n];
    unsigned short hi = f2bf(v);
    L2h[n*128 + k] = hi; L2l[n*128 + k] = f2bf(v - bf2f(hi));
  } else {                           // cast h -> pure-bf16 rows (256B)
    const int i = (b - 544)*256 + t; // over M*16 granules of 16B
    if (i >= M_NODES*16) return;
    const int n = i >> 4, j = i & 15;
    const float4 f0 = *reinterpret_cast<const float4*>(H + (size_t)n*128 + j*8);
    const float4 f1 = *reinterpret_cast<const float4*>(H + (size_t)n*128 + j*8 + 4);
    uint4 hq;
    hq.x = (unsigned)f2bf(f0.x) | ((unsigned)f2bf(f0.y) << 16);
    hq.y = (unsigned)f2bf(f0.z) | ((unsigned)f2bf(f0.w) << 16);
    hq.z = (unsigned)f2bf(f1.x) | ((unsigned)f2bf(f1.y) << 16);
    hq.w = (unsigned)f2bf(f1.z) | ((unsigned)f2bf(f1.w) << 16);
    *reinterpret_cast<uint4*>(X + (size_t)n*256 + j*16) = hq;
  }
}

// ---------- degree histogram: LDS-privatized, packed 2xu16, no global atomics ----------
__global__ __launch_bounds__(256) void k_hist(const int* __restrict__ dst,
    unsigned* __restrict__ part){
  extern __shared__ unsigned lds[];
  const int b = blockIdx.x, tid = threadIdx.x;
  uint4* lds4 = reinterpret_cast<uint4*>(lds);
  for (int j = tid; j < HWORDS/4; j += 256) lds4[j] = make_uint4(0u,0u,0u,0u);
  __syncthreads();
  const int beg = b*EPB, end = beg + EPB;
  for (int e = beg + tid; e < end; e += 256){
    const int d = dst[e];
    atomicAdd(&lds[d >> 1], 1u << ((d & 1)*16));
  }
  __syncthreads();
  unsigned* prow = part + (size_t)b*HWORDS;
  for (int j = tid; j < HWORDS; j += 256) prow[j] = lds[j];
}

// ---------- scan phase 1: block-local prefix over summed partials ----------
__global__ __launch_bounds__(256) void k_scan1(const unsigned* __restrict__ part,
    int* __restrict__ rp, int* __restrict__ bsum){
  __shared__ int wsum[4];
  int b = blockIdx.x, tid = threadIdx.x, lane = tid & 63, w = tid >> 6;
  int i = b*256 + tid;
  int v = 0;
  if (i < M_NODES){
    const int word = i >> 1, sh = (i & 1)*16;
    for (int c = 0; c < B_H; c++)
      v += (part[(size_t)c*HWORDS + word] >> sh) & 0xffffu;
  }
  int x = v;
  #pragma unroll
  for (int off = 1; off < 64; off <<= 1){
    int y = __shfl_up(x, off);
    if (lane >= off) x += y;
  }
  if (lane == 63) wsum[w] = x;
  __syncthreads();
  int pre = 0;
  #pragma unroll
  for (int j = 0; j < 4; j++) if (j < w) pre += wsum[j];
  if (i < M_NODES) rp[i+1] = pre + x;
  if (tid == 255) bsum[b] = pre + x;
}

// ---------- finalize rp + per-block segment bases + gid histogram ----------
__global__ __launch_bounds__(256) void k_cbase(int* __restrict__ rp,
    const int* __restrict__ bsum, const unsigned* __restrict__ part,
    int* __restrict__ cbase, const int* __restrict__ gid, int* __restrict__ gcnt){
  __shared__ int s_bo;
  const int b = blockIdx.x, tid = threadIdx.x;
  const int i = b*256 + tid;
  const bool valid = i < M_NODES;
  const int lane = tid & 63, wave = tid >> 6;
  const int lp = (tid == 0) ? 0 : (valid ? rp[i] : 0);
  const int li = valid ? rp[i+1] : 0;
  if (wave == 0){
    int s = 0;
    for (int j = lane; j < b; j += 64) s += bsum[j];
    #pragma unroll
    for (int off = 32; off > 0; off >>= 1) s += __shfl_xor(s, off);
    if (lane == 0) s_bo = s;
  }
  __syncthreads();
  const int bo = s_bo;
  if (valid) rp[i+1] = li + bo;
  if (i == 0) rp[0] = 0;
  {
    int g = valid ? gid[i] : -1;
    int gp = __shfl_up(g, 1);
    bool bnd = valid && (lane == 0 || g != gp);
    unsigned long long mbnd = __ballot(bnd);
    unsigned long long mval = __ballot(valid);
    if (bnd){
      unsigned long long above = (lane == 63) ? 0ull : (mbnd >> (lane+1));
      int nxt = above ? (lane + 1 + (__ffsll((long long)above) - 1)) : 64;
      int lastvalid = 63 - __clzll((long long)mval);
      int runend = min(nxt, lastvalid + 1);
      atomicAdd(&gcnt[g], runend - lane);
    }
  }
  if (!valid) return;
  const int word = i >> 1, sh = (i & 1)*16;
  int base = lp + bo;
  for (int c = 0; c < B_H; c++){
    cbase[(size_t)c*M_NODES + i] = base;
    base += (part[(size_t)c*HWORDS + word] >> sh) & 0xffffu;
  }
}

// ---------- CSR fill: LDS rank counters, no global atomics ----------
__global__ __launch_bounds__(256) void k_fill(const int* __restrict__ src,
    const int* __restrict__ dst, const int* __restrict__ cbase,
    int* __restrict__ col){
  extern __shared__ unsigned lds[];
  const int b = blockIdx.x, tid = threadIdx.x;
  uint4* lds4 = reinterpret_cast<uint4*>(lds);
  for (int j = tid; j < HWORDS/4; j += 256) lds4[j] = make_uint4(0u,0u,0u,0u);
  __syncthreads();
  const int beg = b*EPB, end = beg + EPB;
  const int* cb = cbase + (size_t)b*M_NODES;
  for (int e = beg + tid; e < end; e += 256){
    const int d = dst[e];
    const int sh = (d & 1)*16;
    const unsigned old = atomicAdd(&lds[d >> 1], 1u << sh);
    const int rank = (old >> sh) & 0xffffu;
    col[cb[d] + rank] = src[e];
  }
}

#define ACC8V(a,u) \
  a[0] += __uint_as_float((u).x << 16); a[1] += __uint_as_float((u).x & 0xFFFF0000u); \
  a[2] += __uint_as_float((u).y << 16); a[3] += __uint_as_float((u).y & 0xFFFF0000u); \
  a[4] += __uint_as_float((u).z << 16); a[5] += __uint_as_float((u).z & 0xFFFF0000u); \
  a[6] += __uint_as_float((u).w << 16); a[7] += __uint_as_float((u).w & 0xFFFF0000u);

// ---------- fused SAGE layer: mean-agg (gather -> LDS) + GEMM [self|agg] x W^T ----------
template<bool RELU>
__global__ __launch_bounds__(256) void k_sage(const char* __restrict__ X,
    const int* __restrict__ rp, const int* __restrict__ col,
    const unsigned short* __restrict__ Wh, const unsigned short* __restrict__ Wl,
    const float* __restrict__ bias, char* __restrict__ Y){
  __shared__ __align__(16) char sG [128*256];   // agg rows (bf16, swizzled granules)
  __shared__ __align__(16) char sA [128*128];
  __shared__ __align__(16) char sBh[128*128];
  __shared__ __align__(16) char sBl[128*128];
  const int tid = threadIdx.x;
  const int wave = tid >> 6, lane = tid & 63;
  const int blockRow = blockIdx.x * 128;

  // ===== gather phase: 2 nodes per quarter-wave in flight, 4-edge unroll each =====
  {
    const int q = tid >> 4, ql = tid & 15;
    const int off = ql*16;
    for (int half = 0; half < 4; half++){
      const int rowA = half*32 + q, rowB = rowA + 16;
      const int vA = blockRow + rowA, vB = blockRow + rowB;
      float aA[8], aB[8];
      #pragma unroll
      for (int k = 0; k < 8; k++){ aA[k] = 0.f; aB[k] = 0.f; }
      int eA = 0, nA = 0, eB = 0, nB = 0;
      if (vA < M_NODES){ eA = rp[vA]; nA = rp[vA+1]; }
      if (vB < M_NODES){ eB = rp[vB]; nB = rp[vB+1]; }
      const int dA = nA - eA, dB = nB - eB;
      while (eA + 4 <= nA && eB + 4 <= nB){
        const int a0 = col[eA], a1 = col[eA+1], a2 = col[eA+2], a3 = col[eA+3];
        const int b0 = col[eB], b1 = col[eB+1], b2 = col[eB+2], b3 = col[eB+3];
        const uint4 xa0 = *reinterpret_cast<const uint4*>(X + (size_t)a0*256 + off);
        const uint4 xa1 = *reinterpret_cast<const uint4*>(X + (size_t)a1*256 + off);
        const uint4 xa2 = *reinterpret_cast<const uint4*>(X + (size_t)a2*256 + off);
        const uint4 xa3 = *reinterpret_cast<const uint4*>(X + (size_t)a3*256 + off);
        const uint4 xb0 = *reinterpret_cast<const uint4*>(X + (size_t)b0*256 + off);
        const uint4 xb1 = *reinterpret_cast<const uint4*>(X + (size_t)b1*256 + off);
        const uint4 xb2 = *reinterpret_cast<const uint4*>(X + (size_t)b2*256 + off);
        const uint4 xb3 = *reinterpret_cast<const uint4*>(X + (size_t)b3*256 + off);
        ACC8V(aA,xa0); ACC8V(aA,xa1); ACC8V(aA,xa2); ACC8V(aA,xa3);
        ACC8V(aB,xb0); ACC8V(aB,xb1); ACC8V(aB,xb2); ACC8V(aB,xb3);
        eA += 4; eB += 4;
      }
      for (; eA + 4 <= nA; eA += 4){
        const int a0 = col[eA], a1 = col[eA+1], a2 = col[eA+2], a3 = col[eA+3];
        const uint4 xa0 = *reinterpret_cast<const uint4*>(X + (size_t)a0*256 + off);
        const uint4 xa1 = *reinterpret_cast<const uint4*>(X + (size_t)a1*256 + off);
        const uint4 xa2 = *reinterpret_cast<const uint4*>(X + (size_t)a2*256 + off);
        const uint4 xa3 = *reinterpret_cast<const uint4*>(X + (size_t)a3*256 + off);
        ACC8V(aA,xa0); ACC8V(aA,xa1); ACC8V(aA,xa2); ACC8V(aA,xa3);
      }
      for (; eB + 4 <= nB; eB += 4){
        const int b0 = col[eB], b1 = col[eB+1], b2 = col[eB+2], b3 = col[eB+3];
        const uint4 xb0 = *reinterpret_cast<const uint4*>(X + (size_t)b0*256 + off);
        const uint4 xb1 = *reinterpret_cast<const uint4*>(X + (size_t)b1*256 + off);
        const uint4 xb2 = *reinterpret_cast<const uint4*>(X + (size_t)b2*256 + off);
        const uint4 xb3 = *reinterpret_cast<const uint4*>(X + (size_t)b3*256 + off);
        ACC8V(aB,xb0); ACC8V(aB,xb1); ACC8V(aB,xb2); ACC8V(aB,xb3);
      }
      for (; eA < nA; eA++){
        const uint4 xa0 = *reinterpret_cast<const uint4*>(X + (size_t)col[eA]*256 + off);
        ACC8V(aA,xa0);
      }
      for (; eB < nB; eB++){
        const uint4 xb0 = *reinterpret_cast<const uint4*>(X + (size_t)col[eB]*256 + off);
        ACC8V(aB,xb0);
      }
      const float invA = 1.f / fmaxf((float)dA, 1.f);
      const float invB = 1.f / fmaxf((float)dB, 1.f);
      uint4 qa, qb;
      unsigned wA[4], wB[4];
      #pragma unroll
      for (int k = 0; k < 4; k++){
        const float xa0 = aA[2*k]*invA, xa1 = aA[2*k+1]*invA;
        const float xb0 = aB[2*k]*invB, xb1 = aB[2*k+1]*invB;
        wA[k] = (unsigned)f2bf(xa0) | ((unsigned)f2bf(xa1) << 16);
        wB[k] = (unsigned)f2bf(xb0) | ((unsigned)f2bf(xb1) << 16);
      }
      qa.x = wA[0]; qa.y = wA[1]; qa.z = wA[2]; qa.w = wA[3];
      qb.x = wB[0]; qb.y = wB[1]; qb.z = wB[2]; qb.w = wB[3];
      *reinterpret_cast<uint4*>(sG + rowA*256 + (off ^ ((rowA & 7) << 4))) = qa;
      *reinterpret_cast<uint4*>(sG + rowB*256 + (off ^ ((rowB & 7) << 4))) = qb;
    }
  }

  // ===== GEMM phase: kc 0,1 self from global X; kc 2,3 agg from sG =====
  const int srow = lane >> 3, slot = lane & 7;
  const int sb = (slot*16) ^ (srow << 4);
  size_t aoff[4];
  #pragma unroll
  for (int i = 0; i < 4; i++){
    int grow = blockRow + wave*32 + i*8 + srow;
    if (grow >= M_NODES) grow = M_NODES - 1;
    aoff[i] = (size_t)grow*256 + sb;
  }
  size_t boff[4];
  #pragma unroll
  for (int i = 0; i < 4; i++){
    int n = wave*32 + i*8 + srow;
    boff[i] = (size_t)n*512 + sb;        // W row stride = 2*KL = 512B
  }
  f32x4 acc[2][8];
  #pragma unroll
  for (int a = 0; a < 2; a++)
    #pragma unroll
    for (int i = 0; i < 8; i++)
      #pragma unroll
      for (int r = 0; r < 4; r++) acc[a][i][r] = 0.f;

  for (int kc = 0; kc < 4; kc++){
    const int bcolb = kc*128;
    __syncthreads();
    if (kc < 2){
      #pragma unroll
      for (int i = 0; i < 4; i++){
        const int lr = (wave*32 + i*8)*128;
        gl_lds16(X + aoff[i] + kc*128, sA + lr);
      }
    }
    #pragma unroll
    for (int i = 0; i < 4; i++){
      const int lr = (wave*32 + i*8)*128;
      gl_lds16(reinterpret_cast<const char*>(Wh) + boff[i] + bcolb, sBh + lr);
      gl_lds16(reinterpret_cast<const char*>(Wl) + boff[i] + bcolb, sBl + lr);
    }
    __syncthreads();
    #pragma unroll
    for (int ks = 0; ks < 2; ks++){
      const int kb = (ks*32 + ((lane >> 4) * 8)) * 2;
      bf16x8 ah[2];
      #pragma unroll
      for (int ar = 0; ar < 2; ar++){
        const int arow = wave*32 + ar*16 + (lane & 15);
        const char* ap = (kc < 2)
            ? (sA + arow*128 + (kb ^ ((arow & 7) << 4)))
            : (sG + arow*256 + (((kc - 2)*128 + kb) ^ ((arow & 7) << 4)));
        ah[ar] = *reinterpret_cast<const bf16x8*>(ap);
      }
      #pragma unroll
      for (int nt = 0; nt < 8; nt++){
        const int n = nt*16 + (lane & 15);
        const int bb = n*128 + (kb ^ ((n & 7) << 4));
        const bf16x8 bh = *reinterpret_cast<const bf16x8*>(sBh + bb);
        const bf16x8 bl = *reinterpret_cast<const bf16x8*>(sBl + bb);
        #pragma unroll
        for (int ar = 0; ar < 2; ar++){
          acc[ar][nt] = __builtin_amdgcn_mfma_f32_16x16x32_bf16(ah[ar], bh, acc[ar][nt], 0, 0, 0);
          acc[ar][nt] = __builtin_amdgcn_mfma_f32_16x16x32_bf16(ah[ar], bl, acc[ar][nt], 0, 0, 0);
        }
      }
    }
  }
  const int r0 = (lane >> 4) * 4;
  #pragma unroll
  for (int ar = 0; ar < 2; ar++){
    const int growb = blockRow + wave*32 + ar*16 + r0;
    #pragma unroll
    for (int nt = 0; nt < 8; nt++){
      const int colx = nt*16 + (lane & 15);
      const float bsv = bias[colx];
      #pragma unroll
      for (int r = 0; r < 4; r++){
        const int grow = growb + r;
        float vv = acc[ar][nt][r] + bsv;
        if (RELU) vv = fmaxf(vv, 0.f);
        const float vo = __shfl_xor(vv, 1);
        if ((lane & 1) == 0 && grow < M_NODES){
          const unsigned hv = (unsigned)f2bf(vv) | ((unsigned)f2bf(vo) << 16);
          *reinterpret_cast<unsigned*>(Y + (size_t)grow*256 + colx*2) = hv;
        }
      }
    }
  }
}

// ---------- fused MLP: 3 layers in one kernel, intermediates in LDS ----------
__global__ __launch_bounds__(256) void k_mlp(const char* __restrict__ X,
    const unsigned short* __restrict__ L0h, const unsigned short* __restrict__ L0l,
    const unsigned short* __restrict__ L1h, const unsigned short* __restrict__ L1l,
    const unsigned short* __restrict__ L2h, const unsigned short* __restrict__ L2l,
    const float* __restrict__ b0, const float* __restrict__ b1,
    const float* __restrict__ b2, float* __restrict__ Y){
  __shared__ __align__(16) char sA [128*128];
  __shared__ __align__(16) char sBh[128*128];
  __shared__ __align__(16) char sBl[128*128];
  __shared__ __align__(16) char sX [2][128*128];
  const int tid = threadIdx.x;
  const int wave = tid >> 6, lane = tid & 63;
  const int blockRow = blockIdx.x * 128;
  const int srow = lane >> 3, slot = lane & 7;
  const int sb = (slot*16) ^ (srow << 4);
  size_t aoff[4];
  #pragma unroll
  for (int i = 0; i < 4; i++){
    int grow = blockRow + wave*32 + i*8 + srow;
    if (grow >= M_NODES) grow = M_NODES - 1;
    aoff[i] = (size_t)grow*256 + sb;
  }
  const int r0 = (lane >> 4) * 4;
  f32x4 acc[2][8];

  // ===== layer 1 =====
  #pragma unroll
  for (int a = 0; a < 2; a++)
    #pragma unroll
    for (int i = 0; i < 8; i++)
      #pragma unroll
      for (int r = 0; r < 4; r++) acc[a][i][r] = 0.f;
  for (int kc = 0; kc < 2; kc++){
    __syncthreads();
    #pragma unroll
    for (int i = 0; i < 4; i++){
      const int lr = (wave*32 + i*8)*128;
      gl_lds16(X + aoff[i] + kc*128, sA + lr);
      const size_t wo = (size_t)(wave*32 + i*8 + srow)*256 + kc*128 + sb;
      gl_lds16(reinterpret_cast<const char*>(L0h) + wo, sBh + lr);
      gl_lds16(reinterpret_cast<const char*>(L0l) + wo, sBl + lr);
    }
    __syncthreads();
    #pragma unroll
    for (int ks = 0; ks < 2; ks++){
      const int kb = (ks*32 + ((lane >> 4) * 8)) * 2;
      bf16x8 ah[2];
      #pragma unroll
      for (int ar = 0; ar < 2; ar++){
        const int arow = wave*32 + ar*16 + (lane & 15);
        ah[ar] = *reinterpret_cast<const bf16x8*>(sA + arow*128 + (kb ^ ((arow & 7) << 4)));
      }
      #pragma unroll
      for (int nt = 0; nt < 8; nt++){
        const int n = nt*16 + (lane & 15);
        const int bb = n*128 + (kb ^ ((n & 7) << 4));
        const bf16x8 bh = *reinterpret_cast<const bf16x8*>(sBh + bb);
        const bf16x8 bl = *reinterpret_cast<const bf16x8*>(sBl + bb);
        #pragma unroll
        for (int ar = 0; ar < 2; ar++){
          acc[ar][nt] = __builtin_amdgcn_mfma_f32_16x16x32_bf16(ah[ar], bh, acc[ar][nt], 0, 0, 0);
          acc[ar][nt] = __builtin_amdgcn_mfma_f32_16x16x32_bf16(ah[ar], bl, acc[ar][nt], 0, 0, 0);
        }
      }
    }
  }
  #pragma unroll
  for (int ar = 0; ar < 2; ar++){
    const int lrow0 = wave*32 + ar*16 + r0;
    #pragma unroll
    for (int nt = 0; nt < 8; nt++){
      const int colx = nt*16 + (lane & 15);
      const float bsv = b0[colx];
      #pragma unroll
      for (int r = 0; r < 4; r++){
        const int lrow = lrow0 + r;
        float vv = fmaxf(acc[ar][nt][r] + bsv, 0.f);
        const float vo = __shfl_xor(vv, 1);
        if ((lane & 1) == 0){
          const unsigned hv = (unsigned)f2bf(vv) | ((unsigned)f2bf(vo) << 16);
          const int k2 = (colx & 63)*2;
          *reinterpret_cast<unsigned*>(sX[colx >> 6] + lrow*128 + (k2 ^ ((lrow & 7) << 4))) = hv;
        }
      }
    }
  }
  // ===== layer 2 =====
  #pragma unroll
  for (int a = 0; a < 2; a++)
    #pragma unroll
    for (int i = 0; i < 8; i++)
      #pragma unroll
      for (int r = 0; r < 4; r++) acc[a][i][r] = 0.f;
  for (int kc = 0; kc < 2; kc++){
    __syncthreads();
    #pragma unroll
    for (int i = 0; i < 4; i++){
      const int lr = (wave*32 + i*8)*128;
      const size_t wo = (size_t)(wave*32 + i*8 + srow)*256 + kc*128 + sb;
      gl_lds16(reinterpret_cast<const char*>(L1h) + wo, sBh + lr);
      gl_lds16(reinterpret_cast<const char*>(L1l) + wo, sBl + lr);
    }
    __syncthreads();
    #pragma unroll
    for (int ks = 0; ks < 2; ks++){
      const int kb = (ks*32 + ((lane >> 4) * 8)) * 2;
      bf16x8 ah[2];
      #pragma unroll
      for (int ar = 0; ar < 2; ar++){
        const int arow = wave*32 + ar*16 + (lane & 15);
        ah[ar] = *reinterpret_cast<const bf16x8*>(sX[kc] + arow*128 + (kb ^ ((arow & 7) << 4)));
      }
      #pragma unroll
      for (int nt = 0; nt < 8; nt++){
        const int n = nt*16 + (lane & 15);
        const int bb = n*128 + (kb ^ ((n & 7) << 4));
        const bf16x8 bh = *reinterpret_cast<const bf16x8*>(sBh + bb);
        const bf16x8 bl = *reinterpret_cast<const bf16x8*>(sBl + bb);
        #pragma unroll
        for (int ar = 0; ar < 2; ar++){
          acc[ar][nt] = __builtin_amdgcn_mfma_f32_16x16x32_bf16(ah[ar], bh, acc[ar][nt], 0, 0, 0);
          acc[ar][nt] = __builtin_amdgcn_mfma_f32_16x16x32_bf16(ah[ar], bl, acc[ar][nt], 0, 0, 0);
        }
      }
    }
  }
  __syncthreads();
  #pragma unroll
  for (int ar = 0; ar < 2; ar++){
    const int lrow0 = wave*32 + ar*16 + r0;
    #pragma unroll
    for (int nt = 0; nt < 8; nt++){
      const int colx = nt*16 + (lane & 15);
      const float bsv = b1[colx];
      #pragma unroll
      for (int r = 0; r < 4; r++){
        const int lrow = lrow0 + r;
        float vv = fmaxf(acc[ar][nt][r] + bsv, 0.f);
        const float vo = __shfl_xor(vv, 1);
        if ((lane & 1) == 0){
          const unsigned hv = (unsigned)f2bf(vv) | ((unsigned)f2bf(vo) << 16);
          const int k2 = (colx & 63)*2;
          *reinterpret_cast<unsigned*>(sX[colx >> 6] + lrow*128 + (k2 ^ ((lrow & 7) << 4))) = hv;
        }
      }
    }
  }
  // ===== layer 3 =====
  #pragma unroll
  for (int a = 0; a < 2; a++)
    #pragma unroll
    for (int i = 0; i < 4; i++)
      #pragma unroll
      for (int r = 0; r < 4; r++) acc[a][i][r] = 0.f;
  for (int kc = 0; kc < 2; kc++){
    __syncthreads();
    #pragma unroll
    for (int i = 0; i < 2; i++){
      const int lr = (wave*16 + i*8)*128;
      const size_t wo = (size_t)(wave*16 + i*8 + srow)*256 + kc*128 + sb;
      gl_lds16(reinterpret_cast<const char*>(L2h) + wo, sBh + lr);
      gl_lds16(reinterpret_cast<const char*>(L2l) + wo, sBl + lr);
    }
    __syncthreads();
    #pragma unroll
    for (int ks = 0; ks < 2; ks++){
      const int kb = (ks*32 + ((lane >> 4) * 8)) * 2;
      bf16x8 ah[2];
      #pragma unroll
      for (int ar = 0; ar < 2; ar++){
        const int arow = wave*32 + ar*16 + (lane & 15);
        ah[ar] = *reinterpret_cast<const bf16x8*>(sX[kc] + arow*128 + (kb ^ ((arow & 7) << 4)));
      }
      #pragma unroll
      for (int nt = 0; nt < 4; nt++){
        const int n = nt*16 + (lane & 15);
        const int bb = n*128 + (kb ^ ((n & 7) << 4));
        const bf16x8 bh = *reinterpret_cast<const bf16x8*>(sBh + bb);
        const bf16x8 bl = *reinterpret_cast<const bf16x8*>(sBl + bb);
        #pragma unroll
        for (int ar = 0; ar < 2; ar++){
          acc[ar][nt] = __builtin_amdgcn_mfma_f32_16x16x32_bf16(ah[ar], bh, acc[ar][nt], 0, 0, 0);
          acc[ar][nt] = __builtin_amdgcn_mfma_f32_16x16x32_bf16(ah[ar], bl, acc[ar][nt], 0, 0, 0);
        }
      }
    }
  }
  #pragma unroll
  for (int ar = 0; ar < 2; ar++){
    const int growb = blockRow + wave*32 + ar*16 + r0;
    #pragma unroll
    for (int nt = 0; nt < 4; nt++){
      const int colx = nt*16 + (lane & 15);
      const float bsv = b2[colx];
      #pragma unroll
      for (int r = 0; r < 4; r++){
        const int grow = growb + r;
        if (grow < M_NODES)
          Y[(size_t)grow*64 + colx] = acc[ar][nt][r] + bsv;
      }
    }
  }
}

// ---------- pooling stage 1: 8 sub-chunks per graph ----------
__global__ __launch_bounds__(256) void k_pool1(const float* __restrict__ Xf,
    const int* __restrict__ gcnt, float* __restrict__ pp){
  const int g = blockIdx.x >> 3, s = blockIdx.x & 7;
  const int tid = threadIdx.x, w = tid >> 6, lane = tid & 63;
  __shared__ int sstart;
  __shared__ float part[4][64];
  if (w == 0){
    int v = gcnt[lane];
    int x = v;
    #pragma unroll
    for (int off = 1; off < 64; off <<= 1){
      int y = __shfl_up(x, off);
      if (lane >= off) x += y;
    }
    if (lane == g) sstart = x - v;
  }
  __syncthreads();
  const int cg = gcnt[g];
  const int Lc = (cg + 7) >> 3;
  const int nbeg = sstart + s*Lc;
  const int nend = min(nbeg + Lc, sstart + cg);
  float a0 = 0.f, a1 = 0.f;
  int i = nbeg + w;
  for (; i + 4 < nend; i += 8){
    a0 += Xf[(size_t)i*64 + lane];
    a1 += Xf[(size_t)(i+4)*64 + lane];
  }
  if (i < nend) a0 += Xf[(size_t)i*64 + lane];
  part[w][lane] = a0 + a1;
  __syncthreads();
  if (w == 0)
    pp[(size_t)(g*8 + s)*64 + lane] = part[0][lane] + part[1][lane] + part[2][lane] + part[3][lane];
}

// ---------- pooling stage 2 ----------
__global__ __launch_bounds__(64) void k_pool2(const float* __restrict__ pp,
    const int* __restrict__ gcnt, float* __restrict__ out){
  const int g = blockIdx.x, lane = threadIdx.x;
  float sum = 0.f;
  #pragma unroll
  for (int s = 0; s < 8; s++) sum += pp[(size_t)(g*8 + s)*64 + lane];
  out[g*64 + lane] = sum / fmaxf((float)gcnt[g], 1.f);
}

extern "C" void kernel_launch(void* const* d_in, const int* in_sizes, int n_in,
                              void* d_out, int out_size, void* d_ws, size_t ws_size,
                              hipStream_t stream){
  const float* h    = (const float*)d_in[0];
  const int*   esrc = (const int*)d_in[1];
  const int*   edst = (const int*)d_in[2];
  const int*   gid  = (const int*)d_in[3];
  const float* ws0  = (const float*)d_in[4];
  const float* wn0  = (const float*)d_in[5];
  const float* bs0  = (const float*)d_in[6];
  const float* ws1  = (const float*)d_in[7];
  const float* wn1  = (const float*)d_in[8];
  const float* bs1  = (const float*)d_in[9];
  const float* ws2  = (const float*)d_in[10];
  const float* wn2  = (const float*)d_in[11];
  const float* bs2  = (const float*)d_in[12];
  const float* lw0  = (const float*)d_in[13];
  const float* lb0  = (const float*)d_in[14];
  const float* lw1  = (const float*)d_in[15];
  const float* lb1  = (const float*)d_in[16];
  const float* lw2  = (const float*)d_in[17];
  const float* lb2  = (const float*)d_in[18];
  float* out = (float*)d_out;

  char* p = (char*)d_ws;
  auto alloc = [&](size_t b)->char*{ char* r = p; p += (b + 255) & ~(size_t)255; return r; };
  char* X0 = alloc((size_t)M_NODES*256);
  char* XA = alloc((size_t)M_NODES*256);
  char* XB = alloc((size_t)M_NODES*256);
  float* xF = (float*)alloc((size_t)M_NODES*64*4);
  float* pp = (float*)alloc((size_t)64*8*64*4);
  char* zbase = p;
  int* gcnt  = (int*)alloc(256);
  size_t zbytes = (size_t)(p - zbase);
  unsigned* part = (unsigned*)alloc((size_t)B_H*HWORDS*4);
  int* cbase = (int*)alloc((size_t)B_H*M_NODES*4);
  int* rp    = (int*)alloc((size_t)(M_NODES+1)*4);
  int* col   = (int*)alloc((size_t)E_EDGES*4);
  int* bsum  = (int*)alloc((size_t)SCAN_B*4);
  unsigned short* W0h = (unsigned short*)alloc(128*256*2);
  unsigned short* W0l = (unsigned short*)alloc(128*256*2);
  unsigned short* W1h = (unsigned short*)alloc(128*256*2);
  unsigned short* W1l = (unsigned short*)alloc(128*256*2);
  unsigned short* W2h = (unsigned short*)alloc(128*256*2);
  unsigned short* W2l = (unsigned short*)alloc(128*256*2);
  unsigned short* L0h = (unsigned short*)alloc(128*128*2);
  unsigned short* L0l = (unsigned short*)alloc(128*128*2);
  unsigned short* L1h = (unsigned short*)alloc(128*128*2);
  unsigned short* L1l = (unsigned short*)alloc(128*128*2);
  unsigned short* L2h = (unsigned short*)alloc(64*128*2);
  unsigned short* L2l = (unsigned short*)alloc(64*128*2);

  hipMemsetAsync(zbase, 0, zbytes, stream);
  k_prep<<<544 + (M_NODES*16 + 255)/256, 256, 0, stream>>>(
      ws0, wn0, ws1, wn1, ws2, wn2, lw0, lw1, lw2, h,
      W0h, W0l, W1h, W1l, W2h, W2l, L0h, L0l, L1h, L1l, L2h, L2l, X0);
  k_hist<<<B_H, 256, HWORDS*4, stream>>>(edst, part);
  k_scan1<<<SCAN_B, 256, 0, stream>>>(part, rp, bsum);
  k_cbase<<<SCAN_B, 256, 0, stream>>>(rp, bsum, part, cbase, gid, gcnt);
  k_fill<<<B_H, 256, HWORDS*4, stream>>>(esrc, edst, cbase, col);

  const int gGrid = (M_NODES + 127)/128;
  // fused SAGE layers
  k_sage<true ><<<gGrid, 256, 0, stream>>>(X0, rp, col, W0h, W0l, bs0, XA);
  k_sage<true ><<<gGrid, 256, 0, stream>>>(XA, rp, col, W1h, W1l, bs1, XB);
  k_sage<false><<<gGrid, 256, 0, stream>>>(XB, rp, col, W2h, W2l, bs2, XA);
  // fused MLP (3 layers)
  k_mlp<<<gGrid, 256, 0, stream>>>(XA, L0h, L0l, L1h, L1l, L2h, L2l, lb0, lb1, lb2, xF);
  // pooling
  k_pool1<<<512, 256, 0, stream>>>(xF, gcnt, pp);
  k_pool2<<<64, 64, 0, stream>>>(pp, gcnt, out);
}

// Round 11
// 220.862 us; speedup vs baseline: 1.1810x; 1.1810x over previous
//
#include <hip/hip_runtime.h>

#define M_NODES 50000
#define E_EDGES 600000
#define SCAN_B ((M_NODES + 255) / 256)
#define B_H 64
#define EPB (E_EDGES / B_H)          // 9375
#define HWORDS (M_NODES / 2)         // 25000 packed u32 = 100 KB LDS

typedef short bf16x8 __attribute__((ext_vector_type(8)));
typedef float f32x4 __attribute__((ext_vector_type(4)));

__device__ __forceinline__ unsigned short f2bf(float f){
  unsigned u = __float_as_uint(f);
  u += 0x7FFFu + ((u >> 16) & 1u);
  return (unsigned short)(u >> 16);
}
__device__ __forceinline__ float bf2f(unsigned short h){
  return __uint_as_float(((unsigned)h) << 16);
}
__device__ __forceinline__ void gl_lds16(const void* g, void* l){
  __builtin_amdgcn_global_load_lds(
      (const __attribute__((address_space(1))) unsigned int*)g,
      (__attribute__((address_space(3))) unsigned int*)l, 16, 0, 0);
}

// ---------- fused: weight prep (split hi/lo, transposed) + activation cast (pure bf16) ----------
__global__ __launch_bounds__(256) void k_prep(
    const float* __restrict__ ws0, const float* __restrict__ wn0,
    const float* __restrict__ ws1, const float* __restrict__ wn1,
    const float* __restrict__ ws2, const float* __restrict__ wn2,
    const float* __restrict__ lw0, const float* __restrict__ lw1,
    const float* __restrict__ lw2, const float* __restrict__ H,
    unsigned short* __restrict__ W0h, unsigned short* __restrict__ W0l,
    unsigned short* __restrict__ W1h, unsigned short* __restrict__ W1l,
    unsigned short* __restrict__ W2h, unsigned short* __restrict__ W2l,
    unsigned short* __restrict__ L0h, unsigned short* __restrict__ L0l,
    unsigned short* __restrict__ L1h, unsigned short* __restrict__ L1l,
    unsigned short* __restrict__ L2h, unsigned short* __restrict__ L2l,
    char* __restrict__ X){
  const int b = blockIdx.x, t = threadIdx.x;
  if (b < 384){                      // stacked [ws;wn] -> [N=128][K=256]
    const int wsel = b >> 7;
    const int i = (b & 127)*256 + t;
    const float* Wa = wsel==0?ws0:(wsel==1?ws1:ws2);
    const float* Wb = wsel==0?wn0:(wsel==1?wn1:wn2);
    unsigned short* Th = wsel==0?W0h:(wsel==1?W1h:W2h);
    unsigned short* Tl = wsel==0?W0l:(wsel==1?W1l:W2l);
    int n = i >> 8, k = i & 255;
    float v = (k < 128) ? Wa[k*128 + n] : Wb[(k-128)*128 + n];
    unsigned short hi = f2bf(v);
    Th[n*256 + k] = hi; Tl[n*256 + k] = f2bf(v - bf2f(hi));
  } else if (b < 512){               // lw0/lw1 [128][128] -> [128][128]^T
    const int lsel = (b - 384) >> 6;
    const int i = ((b - 384) & 63)*256 + t;
    const float* W = lsel==0?lw0:lw1;
    unsigned short* Th = lsel==0?L0h:L1h;
    unsigned short* Tl = lsel==0?L0l:L1l;
    int n = i >> 7, k = i & 127;
    float v = W[k*128 + n];
    unsigned short hi = f2bf(v);
    Th[n*128 + k] = hi; Tl[n*128 + k] = f2bf(v - bf2f(hi));
  } else if (b < 544){               // lw2 [128][64] -> [64][128]^T
    const int i = (b - 512)*256 + t;
    if (i >= 64*128) return;
    int n = i >> 7, k = i & 127;
    float v = lw2[k*64 + n];
    unsigned short hi = f2bf(v);
    L2h[n*128 + k] = hi; L2l[n*128 + k] = f2bf(v - bf2f(hi));
  } else {                           // cast h -> pure-bf16 rows (256B)
    const int i = (b - 544)*256 + t; // over M*16 granules of 16B
    if (i >= M_NODES*16) return;
    const int n = i >> 4, j = i & 15;
    const float4 f0 = *reinterpret_cast<const float4*>(H + (size_t)n*128 + j*8);
    const float4 f1 = *reinterpret_cast<const float4*>(H + (size_t)n*128 + j*8 + 4);
    uint4 hq;
    hq.x = (unsigned)f2bf(f0.x) | ((unsigned)f2bf(f0.y) << 16);
    hq.y = (unsigned)f2bf(f0.z) | ((unsigned)f2bf(f0.w) << 16);
    hq.z = (unsigned)f2bf(f1.x) | ((unsigned)f2bf(f1.y) << 16);
    hq.w = (unsigned)f2bf(f1.z) | ((unsigned)f2bf(f1.w) << 16);
    *reinterpret_cast<uint4*>(X + (size_t)n*256 + j*16) = hq;
  }
}

// ---------- degree histogram: LDS-privatized, packed 2xu16, no global atomics ----------
__global__ __launch_bounds__(256) void k_hist(const int* __restrict__ dst,
    unsigned* __restrict__ part){
  extern __shared__ unsigned lds[];
  const int b = blockIdx.x, tid = threadIdx.x;
  uint4* lds4 = reinterpret_cast<uint4*>(lds);
  for (int j = tid; j < HWORDS/4; j += 256) lds4[j] = make_uint4(0u,0u,0u,0u);
  __syncthreads();
  const int beg = b*EPB, end = beg + EPB;
  for (int e = beg + tid; e < end; e += 256){
    const int d = dst[e];
    atomicAdd(&lds[d >> 1], 1u << ((d & 1)*16));
  }
  __syncthreads();
  unsigned* prow = part + (size_t)b*HWORDS;
  for (int j = tid; j < HWORDS; j += 256) prow[j] = lds[j];
}

// ---------- scan phase 1: block-local prefix over summed partials ----------
__global__ __launch_bounds__(256) void k_scan1(const unsigned* __restrict__ part,
    int* __restrict__ rp, int* __restrict__ bsum){
  __shared__ int wsum[4];
  int b = blockIdx.x, tid = threadIdx.x, lane = tid & 63, w = tid >> 6;
  int i = b*256 + tid;
  int v = 0;
  if (i < M_NODES){
    const int word = i >> 1, sh = (i & 1)*16;
    for (int c = 0; c < B_H; c++)
      v += (part[(size_t)c*HWORDS + word] >> sh) & 0xffffu;
  }
  int x = v;
  #pragma unroll
  for (int off = 1; off < 64; off <<= 1){
    int y = __shfl_up(x, off);
    if (lane >= off) x += y;
  }
  if (lane == 63) wsum[w] = x;
  __syncthreads();
  int pre = 0;
  #pragma unroll
  for (int j = 0; j < 4; j++) if (j < w) pre += wsum[j];
  if (i < M_NODES) rp[i+1] = pre + x;
  if (tid == 255) bsum[b] = pre + x;
}

// ---------- finalize rp + per-block segment bases + gid histogram ----------
__global__ __launch_bounds__(256) void k_cbase(int* __restrict__ rp,
    const int* __restrict__ bsum, const unsigned* __restrict__ part,
    int* __restrict__ cbase, const int* __restrict__ gid, int* __restrict__ gcnt){
  __shared__ int s_bo;
  const int b = blockIdx.x, tid = threadIdx.x;
  const int i = b*256 + tid;
  const bool valid = i < M_NODES;
  const int lane = tid & 63, wave = tid >> 6;
  const int lp = (tid == 0) ? 0 : (valid ? rp[i] : 0);
  const int li = valid ? rp[i+1] : 0;
  if (wave == 0){
    int s = 0;
    for (int j = lane; j < b; j += 64) s += bsum[j];
    #pragma unroll
    for (int off = 32; off > 0; off >>= 1) s += __shfl_xor(s, off);
    if (lane == 0) s_bo = s;
  }
  __syncthreads();
  const int bo = s_bo;
  if (valid) rp[i+1] = li + bo;
  if (i == 0) rp[0] = 0;
  {
    int g = valid ? gid[i] : -1;
    int gp = __shfl_up(g, 1);
    bool bnd = valid && (lane == 0 || g != gp);
    unsigned long long mbnd = __ballot(bnd);
    unsigned long long mval = __ballot(valid);
    if (bnd){
      unsigned long long above = (lane == 63) ? 0ull : (mbnd >> (lane+1));
      int nxt = above ? (lane + 1 + (__ffsll((long long)above) - 1)) : 64;
      int lastvalid = 63 - __clzll((long long)mval);
      int runend = min(nxt, lastvalid + 1);
      atomicAdd(&gcnt[g], runend - lane);
    }
  }
  if (!valid) return;
  const int word = i >> 1, sh = (i & 1)*16;
  int base = lp + bo;
  for (int c = 0; c < B_H; c++){
    cbase[(size_t)c*M_NODES + i] = base;
    base += (part[(size_t)c*HWORDS + word] >> sh) & 0xffffu;
  }
}

// ---------- CSR fill: LDS rank counters, no global atomics ----------
__global__ __launch_bounds__(256) void k_fill(const int* __restrict__ src,
    const int* __restrict__ dst, const int* __restrict__ cbase,
    int* __restrict__ col){
  extern __shared__ unsigned lds[];
  const int b = blockIdx.x, tid = threadIdx.x;
  uint4* lds4 = reinterpret_cast<uint4*>(lds);
  for (int j = tid; j < HWORDS/4; j += 256) lds4[j] = make_uint4(0u,0u,0u,0u);
  __syncthreads();
  const int beg = b*EPB, end = beg + EPB;
  const int* cb = cbase + (size_t)b*M_NODES;
  for (int e = beg + tid; e < end; e += 256){
    const int d = dst[e];
    const int sh = (d & 1)*16;
    const unsigned old = atomicAdd(&lds[d >> 1], 1u << sh);
    const int rank = (old >> sh) & 0xffffu;
    col[cb[d] + rank] = src[e];
  }
}

// ---------- mean aggregation over pure-bf16 rows (256B), quarter-wave per node ----------
#define ACC8(u) \
  a[0] += __uint_as_float((u).x << 16); a[1] += __uint_as_float((u).x & 0xFFFF0000u); \
  a[2] += __uint_as_float((u).y << 16); a[3] += __uint_as_float((u).y & 0xFFFF0000u); \
  a[4] += __uint_as_float((u).z << 16); a[5] += __uint_as_float((u).z & 0xFFFF0000u); \
  a[6] += __uint_as_float((u).w << 16); a[7] += __uint_as_float((u).w & 0xFFFF0000u);

__global__ __launch_bounds__(256) void k_agg(const char* __restrict__ X,
    const int* __restrict__ rp, const int* __restrict__ col, char* __restrict__ G){
  const int q  = threadIdx.x >> 4;          // 16 quarters per block
  const int ql = threadIdx.x & 15;
  const int v = blockIdx.x*16 + q;
  if (v >= M_NODES) return;
  const int beg = rp[v], end = rp[v+1];
  const int off = ql*16;
  float a[8];
  #pragma unroll
  for (int k = 0; k < 8; k++) a[k] = 0.f;
  int e = beg;
  for (; e + 4 <= end; e += 4){
    const int s0 = col[e], s1 = col[e+1], s2 = col[e+2], s3 = col[e+3];
    const uint4 x0 = *reinterpret_cast<const uint4*>(X + (size_t)s0*256 + off);
    const uint4 x1 = *reinterpret_cast<const uint4*>(X + (size_t)s1*256 + off);
    const uint4 x2 = *reinterpret_cast<const uint4*>(X + (size_t)s2*256 + off);
    const uint4 x3 = *reinterpret_cast<const uint4*>(X + (size_t)s3*256 + off);
    ACC8(x0); ACC8(x1); ACC8(x2); ACC8(x3);
  }
  for (; e < end; e++){
    const uint4 x0 = *reinterpret_cast<const uint4*>(X + (size_t)col[e]*256 + off);
    ACC8(x0);
  }
  const float inv = 1.f / fmaxf((float)(end - beg), 1.f);
  uint4 hq;
  unsigned hw[4];
  #pragma unroll
  for (int k = 0; k < 4; k++){
    const float x0 = a[2*k]*inv, x1 = a[2*k+1]*inv;
    hw[k] = (unsigned)f2bf(x0) | ((unsigned)f2bf(x1) << 16);
  }
  hq.x = hw[0]; hq.y = hw[1]; hq.z = hw[2]; hq.w = hw[3];
  *reinterpret_cast<uint4*>(G + (size_t)v*256 + off) = hq;
}

// ---------- SAGE GEMM: MR-row tiles, pure-bf16 A (global_load_lds), split W, 2 MFMAs/tile ----------
template<int MR, int KL, bool RELU>
__global__ __launch_bounds__(256) void k_gemm(
    const char* __restrict__ A1, const char* __restrict__ A2,
    const unsigned short* __restrict__ Wh, const unsigned short* __restrict__ Wl,
    const float* __restrict__ bias, char* __restrict__ Y){
  constexpr int NOUT = 128;
  constexpr int KC = KL / 64;
  constexpr int NAI = MR / 32;        // A stage insts per wave (8 rows each)
  constexpr int AR  = MR / 64;        // 16-row fragments per wave
  __shared__ __align__(16) char sA [MR*128];
  __shared__ __align__(16) char sBh[NOUT*128];
  __shared__ __align__(16) char sBl[NOUT*128];
  const int tid = threadIdx.x;
  const int wave = tid >> 6, lane = tid & 63;
  const int blockRow = blockIdx.x * MR;
  const int srow = lane >> 3, slot = lane & 7;
  const int sb = (slot*16) ^ (srow << 4);
  size_t aoff[NAI];
  #pragma unroll
  for (int i = 0; i < NAI; i++){
    int grow = blockRow + wave*(MR/4) + i*8 + srow;
    if (grow >= M_NODES) grow = M_NODES - 1;
    aoff[i] = (size_t)grow*256 + sb;
  }
  size_t boff[4];
  #pragma unroll
  for (int i = 0; i < 4; i++){
    int n = wave*32 + i*8 + srow;
    boff[i] = (size_t)n*(2*KL) + sb;
  }
  f32x4 acc[AR][8];
  #pragma unroll
  for (int a = 0; a < AR; a++)
    #pragma unroll
    for (int i = 0; i < 8; i++)
      #pragma unroll
      for (int r = 0; r < 4; r++) acc[a][i][r] = 0.f;

  for (int kc = 0; kc < KC; kc++){
    const char* Ap; int acolb;
    if (KL == 256 && kc >= 2){ Ap = A2; acolb = (kc - 2)*128; }
    else                     { Ap = A1; acolb = kc*128; }
    const int bcolb = kc*128;
    __syncthreads();
    #pragma unroll
    for (int i = 0; i < NAI; i++){
      const int lr = (wave*(MR/4) + i*8)*128;
      gl_lds16(Ap + aoff[i] + acolb, sA + lr);
    }
    #pragma unroll
    for (int i = 0; i < 4; i++){
      const int lr = (wave*32 + i*8)*128;
      gl_lds16(reinterpret_cast<const char*>(Wh) + boff[i] + bcolb, sBh + lr);
      gl_lds16(reinterpret_cast<const char*>(Wl) + boff[i] + bcolb, sBl + lr);
    }
    __syncthreads();
    #pragma unroll
    for (int ks = 0; ks < 2; ks++){
      const int kb = (ks*32 + ((lane >> 4) * 8)) * 2;
      bf16x8 ah[AR];
      #pragma unroll
      for (int ar = 0; ar < AR; ar++){
        const int arow = wave*(MR/4) + ar*16 + (lane & 15);
        ah[ar] = *reinterpret_cast<const bf16x8*>(sA + arow*128 + (kb ^ ((arow & 7) << 4)));
      }
      #pragma unroll
      for (int nt = 0; nt < 8; nt++){
        const int n = nt*16 + (lane & 15);
        const int bb = n*128 + (kb ^ ((n & 7) << 4));
        const bf16x8 bh = *reinterpret_cast<const bf16x8*>(sBh + bb);
        const bf16x8 bl = *reinterpret_cast<const bf16x8*>(sBl + bb);
        #pragma unroll
        for (int ar = 0; ar < AR; ar++){
          acc[ar][nt] = __builtin_amdgcn_mfma_f32_16x16x32_bf16(ah[ar], bh, acc[ar][nt], 0, 0, 0);
          acc[ar][nt] = __builtin_amdgcn_mfma_f32_16x16x32_bf16(ah[ar], bl, acc[ar][nt], 0, 0, 0);
        }
      }
    }
  }
  const int r0 = (lane >> 4) * 4;
  #pragma unroll
  for (int ar = 0; ar < AR; ar++){
    const int growb = blockRow + wave*(MR/4) + ar*16 + r0;
    #pragma unroll
    for (int nt = 0; nt < 8; nt++){
      const int colx = nt*16 + (lane & 15);
      const float bsv = bias[colx];
      #pragma unroll
      for (int r = 0; r < 4; r++){
        const int grow = growb + r;
        float vv = acc[ar][nt][r] + bsv;
        if (RELU) vv = fmaxf(vv, 0.f);
        const float vo = __shfl_xor(vv, 1);
        if ((lane & 1) == 0 && grow < M_NODES){
          const unsigned hv = (unsigned)f2bf(vv) | ((unsigned)f2bf(vo) << 16);
          *reinterpret_cast<unsigned*>(Y + (size_t)grow*256 + colx*2) = hv;
        }
      }
    }
  }
}

// ---------- fused MLP: 3 layers in one kernel, intermediates in LDS ----------
__global__ __launch_bounds__(256) void k_mlp(const char* __restrict__ X,
    const unsigned short* __restrict__ L0h, const unsigned short* __restrict__ L0l,
    const unsigned short* __restrict__ L1h, const unsigned short* __restrict__ L1l,
    const unsigned short* __restrict__ L2h, const unsigned short* __restrict__ L2l,
    const float* __restrict__ b0, const float* __restrict__ b1,
    const float* __restrict__ b2, float* __restrict__ Y){
  __shared__ __align__(16) char sA [128*128];
  __shared__ __align__(16) char sBh[128*128];
  __shared__ __align__(16) char sBl[128*128];
  __shared__ __align__(16) char sX [2][128*128];
  const int tid = threadIdx.x;
  const int wave = tid >> 6, lane = tid & 63;
  const int blockRow = blockIdx.x * 128;
  const int srow = lane >> 3, slot = lane & 7;
  const int sb = (slot*16) ^ (srow << 4);
  size_t aoff[4];
  #pragma unroll
  for (int i = 0; i < 4; i++){
    int grow = blockRow + wave*32 + i*8 + srow;
    if (grow >= M_NODES) grow = M_NODES - 1;
    aoff[i] = (size_t)grow*256 + sb;
  }
  const int r0 = (lane >> 4) * 4;
  f32x4 acc[2][8];

  // ===== layer 1 =====
  #pragma unroll
  for (int a = 0; a < 2; a++)
    #pragma unroll
    for (int i = 0; i < 8; i++)
      #pragma unroll
      for (int r = 0; r < 4; r++) acc[a][i][r] = 0.f;
  for (int kc = 0; kc < 2; kc++){
    __syncthreads();
    #pragma unroll
    for (int i = 0; i < 4; i++){
      const int lr = (wave*32 + i*8)*128;
      gl_lds16(X + aoff[i] + kc*128, sA + lr);
      const size_t wo = (size_t)(wave*32 + i*8 + srow)*256 + kc*128 + sb;
      gl_lds16(reinterpret_cast<const char*>(L0h) + wo, sBh + lr);
      gl_lds16(reinterpret_cast<const char*>(L0l) + wo, sBl + lr);
    }
    __syncthreads();
    #pragma unroll
    for (int ks = 0; ks < 2; ks++){
      const int kb = (ks*32 + ((lane >> 4) * 8)) * 2;
      bf16x8 ah[2];
      #pragma unroll
      for (int ar = 0; ar < 2; ar++){
        const int arow = wave*32 + ar*16 + (lane & 15);
        ah[ar] = *reinterpret_cast<const bf16x8*>(sA + arow*128 + (kb ^ ((arow & 7) << 4)));
      }
      #pragma unroll
      for (int nt = 0; nt < 8; nt++){
        const int n = nt*16 + (lane & 15);
        const int bb = n*128 + (kb ^ ((n & 7) << 4));
        const bf16x8 bh = *reinterpret_cast<const bf16x8*>(sBh + bb);
        const bf16x8 bl = *reinterpret_cast<const bf16x8*>(sBl + bb);
        #pragma unroll
        for (int ar = 0; ar < 2; ar++){
          acc[ar][nt] = __builtin_amdgcn_mfma_f32_16x16x32_bf16(ah[ar], bh, acc[ar][nt], 0, 0, 0);
          acc[ar][nt] = __builtin_amdgcn_mfma_f32_16x16x32_bf16(ah[ar], bl, acc[ar][nt], 0, 0, 0);
        }
      }
    }
  }
  #pragma unroll
  for (int ar = 0; ar < 2; ar++){
    const int lrow0 = wave*32 + ar*16 + r0;
    #pragma unroll
    for (int nt = 0; nt < 8; nt++){
      const int colx = nt*16 + (lane & 15);
      const float bsv = b0[colx];
      #pragma unroll
      for (int r = 0; r < 4; r++){
        const int lrow = lrow0 + r;
        float vv = fmaxf(acc[ar][nt][r] + bsv, 0.f);
        const float vo = __shfl_xor(vv, 1);
        if ((lane & 1) == 0){
          const unsigned hv = (unsigned)f2bf(vv) | ((unsigned)f2bf(vo) << 16);
          const int k2 = (colx & 63)*2;
          *reinterpret_cast<unsigned*>(sX[colx >> 6] + lrow*128 + (k2 ^ ((lrow & 7) << 4))) = hv;
        }
      }
    }
  }
  // ===== layer 2 =====
  #pragma unroll
  for (int a = 0; a < 2; a++)
    #pragma unroll
    for (int i = 0; i < 8; i++)
      #pragma unroll
      for (int r = 0; r < 4; r++) acc[a][i][r] = 0.f;
  for (int kc = 0; kc < 2; kc++){
    __syncthreads();
    #pragma unroll
    for (int i = 0; i < 4; i++){
      const int lr = (wave*32 + i*8)*128;
      const size_t wo = (size_t)(wave*32 + i*8 + srow)*256 + kc*128 + sb;
      gl_lds16(reinterpret_cast<const char*>(L1h) + wo, sBh + lr);
      gl_lds16(reinterpret_cast<const char*>(L1l) + wo, sBl + lr);
    }
    __syncthreads();
    #pragma unroll
    for (int ks = 0; ks < 2; ks++){
      const int kb = (ks*32 + ((lane >> 4) * 8)) * 2;
      bf16x8 ah[2];
      #pragma unroll
      for (int ar = 0; ar < 2; ar++){
        const int arow = wave*32 + ar*16 + (lane & 15);
        ah[ar] = *reinterpret_cast<const bf16x8*>(sX[kc] + arow*128 + (kb ^ ((arow & 7) << 4)));
      }
      #pragma unroll
      for (int nt = 0; nt < 8; nt++){
        const int n = nt*16 + (lane & 15);
        const int bb = n*128 + (kb ^ ((n & 7) << 4));
        const bf16x8 bh = *reinterpret_cast<const bf16x8*>(sBh + bb);
        const bf16x8 bl = *reinterpret_cast<const bf16x8*>(sBl + bb);
        #pragma unroll
        for (int ar = 0; ar < 2; ar++){
          acc[ar][nt] = __builtin_amdgcn_mfma_f32_16x16x32_bf16(ah[ar], bh, acc[ar][nt], 0, 0, 0);
          acc[ar][nt] = __builtin_amdgcn_mfma_f32_16x16x32_bf16(ah[ar], bl, acc[ar][nt], 0, 0, 0);
        }
      }
    }
  }
  __syncthreads();
  #pragma unroll
  for (int ar = 0; ar < 2; ar++){
    const int lrow0 = wave*32 + ar*16 + r0;
    #pragma unroll
    for (int nt = 0; nt < 8; nt++){
      const int colx = nt*16 + (lane & 15);
      const float bsv = b1[colx];
      #pragma unroll
      for (int r = 0; r < 4; r++){
        const int lrow = lrow0 + r;
        float vv = fmaxf(acc[ar][nt][r] + bsv, 0.f);
        const float vo = __shfl_xor(vv, 1);
        if ((lane & 1) == 0){
          const unsigned hv = (unsigned)f2bf(vv) | ((unsigned)f2bf(vo) << 16);
          const int k2 = (colx & 63)*2;
          *reinterpret_cast<unsigned*>(sX[colx >> 6] + lrow*128 + (k2 ^ ((lrow & 7) << 4))) = hv;
        }
      }
    }
  }
  // ===== layer 3 =====
  #pragma unroll
  for (int a = 0; a < 2; a++)
    #pragma unroll
    for (int i = 0; i < 4; i++)
      #pragma unroll
      for (int r = 0; r < 4; r++) acc[a][i][r] = 0.f;
  for (int kc = 0; kc < 2; kc++){
    __syncthreads();
    #pragma unroll
    for (int i = 0; i < 2; i++){
      const int lr = (wave*16 + i*8)*128;
      const size_t wo = (size_t)(wave*16 + i*8 + srow)*256 + kc*128 + sb;
      gl_lds16(reinterpret_cast<const char*>(L2h) + wo, sBh + lr);
      gl_lds16(reinterpret_cast<const char*>(L2l) + wo, sBl + lr);
    }
    __syncthreads();
    #pragma unroll
    for (int ks = 0; ks < 2; ks++){
      const int kb = (ks*32 + ((lane >> 4) * 8)) * 2;
      bf16x8 ah[2];
      #pragma unroll
      for (int ar = 0; ar < 2; ar++){
        const int arow = wave*32 + ar*16 + (lane & 15);
        ah[ar] = *reinterpret_cast<const bf16x8*>(sX[kc] + arow*128 + (kb ^ ((arow & 7) << 4)));
      }
      #pragma unroll
      for (int nt = 0; nt < 4; nt++){
        const int n = nt*16 + (lane & 15);
        const int bb = n*128 + (kb ^ ((n & 7) << 4));
        const bf16x8 bh = *reinterpret_cast<const bf16x8*>(sBh + bb);
        const bf16x8 bl = *reinterpret_cast<const bf16x8*>(sBl + bb);
        #pragma unroll
        for (int ar = 0; ar < 2; ar++){
          acc[ar][nt] = __builtin_amdgcn_mfma_f32_16x16x32_bf16(ah[ar], bh, acc[ar][nt], 0, 0, 0);
          acc[ar][nt] = __builtin_amdgcn_mfma_f32_16x16x32_bf16(ah[ar], bl, acc[ar][nt], 0, 0, 0);
        }
      }
    }
  }
  #pragma unroll
  for (int ar = 0; ar < 2; ar++){
    const int growb = blockRow + wave*32 + ar*16 + r0;
    #pragma unroll
    for (int nt = 0; nt < 4; nt++){
      const int colx = nt*16 + (lane & 15);
      const float bsv = b2[colx];
      #pragma unroll
      for (int r = 0; r < 4; r++){
        const int grow = growb + r;
        if (grow < M_NODES)
          Y[(size_t)grow*64 + colx] = acc[ar][nt][r] + bsv;
      }
    }
  }
}

// ---------- pooling stage 1: 8 sub-chunks per graph ----------
__global__ __launch_bounds__(256) void k_pool1(const float* __restrict__ Xf,
    const int* __restrict__ gcnt, float* __restrict__ pp){
  const int g = blockIdx.x >> 3, s = blockIdx.x & 7;
  const int tid = threadIdx.x, w = tid >> 6, lane = tid & 63;
  __shared__ int sstart;
  __shared__ float part[4][64];
  if (w == 0){
    int v = gcnt[lane];
    int x = v;
    #pragma unroll
    for (int off = 1; off < 64; off <<= 1){
      int y = __shfl_up(x, off);
      if (lane >= off) x += y;
    }
    if (lane == g) sstart = x - v;
  }
  __syncthreads();
  const int cg = gcnt[g];
  const int Lc = (cg + 7) >> 3;
  const int nbeg = sstart + s*Lc;
  const int nend = min(nbeg + Lc, sstart + cg);
  float a0 = 0.f, a1 = 0.f;
  int i = nbeg + w;
  for (; i + 4 < nend; i += 8){
    a0 += Xf[(size_t)i*64 + lane];
    a1 += Xf[(size_t)(i+4)*64 + lane];
  }
  if (i < nend) a0 += Xf[(size_t)i*64 + lane];
  part[w][lane] = a0 + a1;
  __syncthreads();
  if (w == 0)
    pp[(size_t)(g*8 + s)*64 + lane] = part[0][lane] + part[1][lane] + part[2][lane] + part[3][lane];
}

// ---------- pooling stage 2 ----------
__global__ __launch_bounds__(64) void k_pool2(const float* __restrict__ pp,
    const int* __restrict__ gcnt, float* __restrict__ out){
  const int g = blockIdx.x, lane = threadIdx.x;
  float sum = 0.f;
  #pragma unroll
  for (int s = 0; s < 8; s++) sum += pp[(size_t)(g*8 + s)*64 + lane];
  out[g*64 + lane] = sum / fmaxf((float)gcnt[g], 1.f);
}

extern "C" void kernel_launch(void* const* d_in, const int* in_sizes, int n_in,
                              void* d_out, int out_size, void* d_ws, size_t ws_size,
                              hipStream_t stream){
  const float* h    = (const float*)d_in[0];
  const int*   esrc = (const int*)d_in[1];
  const int*   edst = (const int*)d_in[2];
  const int*   gid  = (const int*)d_in[3];
  const float* ws0  = (const float*)d_in[4];
  const float* wn0  = (const float*)d_in[5];
  const float* bs0  = (const float*)d_in[6];
  const float* ws1  = (const float*)d_in[7];
  const float* wn1  = (const float*)d_in[8];
  const float* bs1  = (const float*)d_in[9];
  const float* ws2  = (const float*)d_in[10];
  const float* wn2  = (const float*)d_in[11];
  const float* bs2  = (const float*)d_in[12];
  const float* lw0  = (const float*)d_in[13];
  const float* lb0  = (const float*)d_in[14];
  const float* lw1  = (const float*)d_in[15];
  const float* lb1  = (const float*)d_in[16];
  const float* lw2  = (const float*)d_in[17];
  const float* lb2  = (const float*)d_in[18];
  float* out = (float*)d_out;

  char* p = (char*)d_ws;
  auto alloc = [&](size_t b)->char*{ char* r = p; p += (b + 255) & ~(size_t)255; return r; };
  char* X0 = alloc((size_t)M_NODES*256);
  char* XA = alloc((size_t)M_NODES*256);
  char* XB = alloc((size_t)M_NODES*256);
  char* G  = alloc((size_t)M_NODES*256);
  float* xF = (float*)alloc((size_t)M_NODES*64*4);
  float* pp = (float*)alloc((size_t)64*8*64*4);
  char* zbase = p;
  int* gcnt  = (int*)alloc(256);
  size_t zbytes = (size_t)(p - zbase);
  unsigned* part = (unsigned*)alloc((size_t)B_H*HWORDS*4);
  int* cbase = (int*)alloc((size_t)B_H*M_NODES*4);
  int* rp    = (int*)alloc((size_t)(M_NODES+1)*4);
  int* col   = (int*)alloc((size_t)E_EDGES*4);
  int* bsum  = (int*)alloc((size_t)SCAN_B*4);
  unsigned short* W0h = (unsigned short*)alloc(128*256*2);
  unsigned short* W0l = (unsigned short*)alloc(128*256*2);
  unsigned short* W1h = (unsigned short*)alloc(128*256*2);
  unsigned short* W1l = (unsigned short*)alloc(128*256*2);
  unsigned short* W2h = (unsigned short*)alloc(128*256*2);
  unsigned short* W2l = (unsigned short*)alloc(128*256*2);
  unsigned short* L0h = (unsigned short*)alloc(128*128*2);
  unsigned short* L0l = (unsigned short*)alloc(128*128*2);
  unsigned short* L1h = (unsigned short*)alloc(128*128*2);
  unsigned short* L1l = (unsigned short*)alloc(128*128*2);
  unsigned short* L2h = (unsigned short*)alloc(64*128*2);
  unsigned short* L2l = (unsigned short*)alloc(64*128*2);

  hipMemsetAsync(zbase, 0, zbytes, stream);
  k_prep<<<544 + (M_NODES*16 + 255)/256, 256, 0, stream>>>(
      ws0, wn0, ws1, wn1, ws2, wn2, lw0, lw1, lw2, h,
      W0h, W0l, W1h, W1l, W2h, W2l, L0h, L0l, L1h, L1l, L2h, L2l, X0);
  k_hist<<<B_H, 256, HWORDS*4, stream>>>(edst, part);
  k_scan1<<<SCAN_B, 256, 0, stream>>>(part, rp, bsum);
  k_cbase<<<SCAN_B, 256, 0, stream>>>(rp, bsum, part, cbase, gid, gcnt);
  k_fill<<<B_H, 256, HWORDS*4, stream>>>(esrc, edst, cbase, col);

  const int sGrid = (M_NODES + 63)/64;
  const int mGrid = (M_NODES + 127)/128;
  const int aGrid = (M_NODES + 15)/16;
  // SAGE layer 0 (relu)
  k_agg<<<aGrid, 256, 0, stream>>>(X0, rp, col, G);
  k_gemm<64,256,true ><<<sGrid,256,0,stream>>>(X0, G, W0h, W0l, bs0, XA);
  // SAGE layer 1 (relu)
  k_agg<<<aGrid, 256, 0, stream>>>(XA, rp, col, G);
  k_gemm<64,256,true ><<<sGrid,256,0,stream>>>(XA, G, W1h, W1l, bs1, XB);
  // SAGE layer 2 (no relu)
  k_agg<<<aGrid, 256, 0, stream>>>(XB, rp, col, G);
  k_gemm<64,256,false><<<sGrid,256,0,stream>>>(XB, G, W2h, W2l, bs2, XA);
  // fused MLP (3 layers)
  k_mlp<<<mGrid, 256, 0, stream>>>(XA, L0h, L0l, L1h, L1l, L2h, L2l, lb0, lb1, lb2, xF);
  // pooling
  k_pool1<<<512, 256, 0, stream>>>(xF, gcnt, pp);
  k_pool2<<<64, 64, 0, stream>>>(pp, gcnt, out);
}

// Round 12
// 215.883 us; speedup vs baseline: 1.2082x; 1.0231x over previous
//
#include <hip/hip_runtime.h>

#define M_NODES 50000
#define E_EDGES 600000
#define SCAN_B ((M_NODES + 255) / 256)
#define B_H 64
#define EPB (E_EDGES / B_H)          // 9375
#define HWORDS (M_NODES / 2)         // 25000 packed u32 = 100 KB LDS

typedef short bf16x8 __attribute__((ext_vector_type(8)));
typedef float f32x4 __attribute__((ext_vector_type(4)));

__device__ __forceinline__ unsigned short f2bf(float f){
  unsigned u = __float_as_uint(f);
  u += 0x7FFFu + ((u >> 16) & 1u);
  return (unsigned short)(u >> 16);
}
__device__ __forceinline__ float bf2f(unsigned short h){
  return __uint_as_float(((unsigned)h) << 16);
}
__device__ __forceinline__ void gl_lds16(const void* g, void* l){
  __builtin_amdgcn_global_load_lds(
      (const __attribute__((address_space(1))) unsigned int*)g,
      (__attribute__((address_space(3))) unsigned int*)l, 16, 0, 0);
}

// ---------- fused: weight prep (split hi/lo, transposed) + activation cast (pure bf16) ----------
__global__ __launch_bounds__(256) void k_prep(
    const float* __restrict__ ws0, const float* __restrict__ wn0,
    const float* __restrict__ ws1, const float* __restrict__ wn1,
    const float* __restrict__ ws2, const float* __restrict__ wn2,
    const float* __restrict__ lw0, const float* __restrict__ lw1,
    const float* __restrict__ lw2, const float* __restrict__ H,
    unsigned short* __restrict__ W0h, unsigned short* __restrict__ W0l,
    unsigned short* __restrict__ W1h, unsigned short* __restrict__ W1l,
    unsigned short* __restrict__ W2h, unsigned short* __restrict__ W2l,
    unsigned short* __restrict__ L0h, unsigned short* __restrict__ L0l,
    unsigned short* __restrict__ L1h, unsigned short* __restrict__ L1l,
    unsigned short* __restrict__ L2h, unsigned short* __restrict__ L2l,
    char* __restrict__ X){
  const int b = blockIdx.x, t = threadIdx.x;
  if (b < 384){                      // stacked [ws;wn] -> [N=128][K=256]
    const int wsel = b >> 7;
    const int i = (b & 127)*256 + t;
    const float* Wa = wsel==0?ws0:(wsel==1?ws1:ws2);
    const float* Wb = wsel==0?wn0:(wsel==1?wn1:wn2);
    unsigned short* Th = wsel==0?W0h:(wsel==1?W1h:W2h);
    unsigned short* Tl = wsel==0?W0l:(wsel==1?W1l:W2l);
    int n = i >> 8, k = i & 255;
    float v = (k < 128) ? Wa[k*128 + n] : Wb[(k-128)*128 + n];
    unsigned short hi = f2bf(v);
    Th[n*256 + k] = hi; Tl[n*256 + k] = f2bf(v - bf2f(hi));
  } else if (b < 512){               // lw0/lw1 [128][128] -> [128][128]^T
    const int lsel = (b - 384) >> 6;
    const int i = ((b - 384) & 63)*256 + t;
    const float* W = lsel==0?lw0:lw1;
    unsigned short* Th = lsel==0?L0h:L1h;
    unsigned short* Tl = lsel==0?L0l:L1l;
    int n = i >> 7, k = i & 127;
    float v = W[k*128 + n];
    unsigned short hi = f2bf(v);
    Th[n*128 + k] = hi; Tl[n*128 + k] = f2bf(v - bf2f(hi));
  } else if (b < 544){               // lw2 [128][64] -> [64][128]^T
    const int i = (b - 512)*256 + t;
    if (i >= 64*128) return;
    int n = i >> 7, k = i & 127;
    float v = lw2[k*64 + n];
    unsigned short hi = f2bf(v);
    L2h[n*128 + k] = hi; L2l[n*128 + k] = f2bf(v - bf2f(hi));
  } else {                           // cast h -> pure-bf16 rows (256B)
    const int i = (b - 544)*256 + t; // over M*16 granules of 16B
    if (i >= M_NODES*16) return;
    const int n = i >> 4, j = i & 15;
    const float4 f0 = *reinterpret_cast<const float4*>(H + (size_t)n*128 + j*8);
    const float4 f1 = *reinterpret_cast<const float4*>(H + (size_t)n*128 + j*8 + 4);
    uint4 hq;
    hq.x = (unsigned)f2bf(f0.x) | ((unsigned)f2bf(f0.y) << 16);
    hq.y = (unsigned)f2bf(f0.z) | ((unsigned)f2bf(f0.w) << 16);
    hq.z = (unsigned)f2bf(f1.x) | ((unsigned)f2bf(f1.y) << 16);
    hq.w = (unsigned)f2bf(f1.z) | ((unsigned)f2bf(f1.w) << 16);
    *reinterpret_cast<uint4*>(X + (size_t)n*256 + j*16) = hq;
  }
}

// ---------- degree histogram: LDS-privatized, packed 2xu16, no global atomics ----------
__global__ __launch_bounds__(256) void k_hist(const int* __restrict__ dst,
    unsigned* __restrict__ part){
  extern __shared__ unsigned lds[];
  const int b = blockIdx.x, tid = threadIdx.x;
  uint4* lds4 = reinterpret_cast<uint4*>(lds);
  for (int j = tid; j < HWORDS/4; j += 256) lds4[j] = make_uint4(0u,0u,0u,0u);
  __syncthreads();
  const int beg = b*EPB, end = beg + EPB;
  for (int e = beg + tid; e < end; e += 256){
    const int d = dst[e];
    atomicAdd(&lds[d >> 1], 1u << ((d & 1)*16));
  }
  __syncthreads();
  unsigned* prow = part + (size_t)b*HWORDS;
  for (int j = tid; j < HWORDS; j += 256) prow[j] = lds[j];
}

// ---------- scan phase 1: block-local prefix over summed partials ----------
__global__ __launch_bounds__(256) void k_scan1(const unsigned* __restrict__ part,
    int* __restrict__ rp, int* __restrict__ bsum){
  __shared__ int wsum[4];
  int b = blockIdx.x, tid = threadIdx.x, lane = tid & 63, w = tid >> 6;
  int i = b*256 + tid;
  int v = 0;
  if (i < M_NODES){
    const int word = i >> 1, sh = (i & 1)*16;
    for (int c = 0; c < B_H; c++)
      v += (part[(size_t)c*HWORDS + word] >> sh) & 0xffffu;
  }
  int x = v;
  #pragma unroll
  for (int off = 1; off < 64; off <<= 1){
    int y = __shfl_up(x, off);
    if (lane >= off) x += y;
  }
  if (lane == 63) wsum[w] = x;
  __syncthreads();
  int pre = 0;
  #pragma unroll
  for (int j = 0; j < 4; j++) if (j < w) pre += wsum[j];
  if (i < M_NODES) rp[i+1] = pre + x;
  if (tid == 255) bsum[b] = pre + x;
}

// ---------- finalize rp + per-block segment bases + gid histogram ----------
__global__ __launch_bounds__(256) void k_cbase(int* __restrict__ rp,
    const int* __restrict__ bsum, const unsigned* __restrict__ part,
    int* __restrict__ cbase, const int* __restrict__ gid, int* __restrict__ gcnt){
  __shared__ int s_bo;
  const int b = blockIdx.x, tid = threadIdx.x;
  const int i = b*256 + tid;
  const bool valid = i < M_NODES;
  const int lane = tid & 63, wave = tid >> 6;
  const int lp = (tid == 0) ? 0 : (valid ? rp[i] : 0);
  const int li = valid ? rp[i+1] : 0;
  if (wave == 0){
    int s = 0;
    for (int j = lane; j < b; j += 64) s += bsum[j];
    #pragma unroll
    for (int off = 32; off > 0; off >>= 1) s += __shfl_xor(s, off);
    if (lane == 0) s_bo = s;
  }
  __syncthreads();
  const int bo = s_bo;
  if (valid) rp[i+1] = li + bo;
  if (i == 0) rp[0] = 0;
  {
    int g = valid ? gid[i] : -1;
    int gp = __shfl_up(g, 1);
    bool bnd = valid && (lane == 0 || g != gp);
    unsigned long long mbnd = __ballot(bnd);
    unsigned long long mval = __ballot(valid);
    if (bnd){
      unsigned long long above = (lane == 63) ? 0ull : (mbnd >> (lane+1));
      int nxt = above ? (lane + 1 + (__ffsll((long long)above) - 1)) : 64;
      int lastvalid = 63 - __clzll((long long)mval);
      int runend = min(nxt, lastvalid + 1);
      atomicAdd(&gcnt[g], runend - lane);
    }
  }
  if (!valid) return;
  const int word = i >> 1, sh = (i & 1)*16;
  int base = lp + bo;
  for (int c = 0; c < B_H; c++){
    cbase[(size_t)c*M_NODES + i] = base;
    base += (part[(size_t)c*HWORDS + word] >> sh) & 0xffffu;
  }
}

// ---------- CSR fill: LDS rank counters, no global atomics ----------
__global__ __launch_bounds__(256) void k_fill(const int* __restrict__ src,
    const int* __restrict__ dst, const int* __restrict__ cbase,
    int* __restrict__ col){
  extern __shared__ unsigned lds[];
  const int b = blockIdx.x, tid = threadIdx.x;
  uint4* lds4 = reinterpret_cast<uint4*>(lds);
  for (int j = tid; j < HWORDS/4; j += 256) lds4[j] = make_uint4(0u,0u,0u,0u);
  __syncthreads();
  const int beg = b*EPB, end = beg + EPB;
  const int* cb = cbase + (size_t)b*M_NODES;
  for (int e = beg + tid; e < end; e += 256){
    const int d = dst[e];
    const int sh = (d & 1)*16;
    const unsigned old = atomicAdd(&lds[d >> 1], 1u << sh);
    const int rank = (old >> sh) & 0xffffu;
    col[cb[d] + rank] = src[e];
  }
}

// ---------- mean aggregation over pure-bf16 rows (256B), quarter-wave per node ----------
#define ACC8(u) \
  a[0] += __uint_as_float((u).x << 16); a[1] += __uint_as_float((u).x & 0xFFFF0000u); \
  a[2] += __uint_as_float((u).y << 16); a[3] += __uint_as_float((u).y & 0xFFFF0000u); \
  a[4] += __uint_as_float((u).z << 16); a[5] += __uint_as_float((u).z & 0xFFFF0000u); \
  a[6] += __uint_as_float((u).w << 16); a[7] += __uint_as_float((u).w & 0xFFFF0000u);

__global__ __launch_bounds__(256) void k_agg(const char* __restrict__ X,
    const int* __restrict__ rp, const int* __restrict__ col, char* __restrict__ G){
  const int q  = threadIdx.x >> 4;          // 16 quarters per block
  const int ql = threadIdx.x & 15;
  const int v = blockIdx.x*16 + q;
  if (v >= M_NODES) return;
  const int beg = rp[v], end = rp[v+1];
  const int off = ql*16;
  float a[8];
  #pragma unroll
  for (int k = 0; k < 8; k++) a[k] = 0.f;
  int e = beg;
  for (; e + 4 <= end; e += 4){
    const int s0 = col[e], s1 = col[e+1], s2 = col[e+2], s3 = col[e+3];
    const uint4 x0 = *reinterpret_cast<const uint4*>(X + (size_t)s0*256 + off);
    const uint4 x1 = *reinterpret_cast<const uint4*>(X + (size_t)s1*256 + off);
    const uint4 x2 = *reinterpret_cast<const uint4*>(X + (size_t)s2*256 + off);
    const uint4 x3 = *reinterpret_cast<const uint4*>(X + (size_t)s3*256 + off);
    ACC8(x0); ACC8(x1); ACC8(x2); ACC8(x3);
  }
  for (; e < end; e++){
    const uint4 x0 = *reinterpret_cast<const uint4*>(X + (size_t)col[e]*256 + off);
    ACC8(x0);
  }
  const float inv = 1.f / fmaxf((float)(end - beg), 1.f);
  uint4 hq;
  unsigned hw[4];
  #pragma unroll
  for (int k = 0; k < 4; k++){
    const float x0 = a[2*k]*inv, x1 = a[2*k+1]*inv;
    hw[k] = (unsigned)f2bf(x0) | ((unsigned)f2bf(x1) << 16);
  }
  hq.x = hw[0]; hq.y = hw[1]; hq.z = hw[2]; hq.w = hw[3];
  *reinterpret_cast<uint4*>(G + (size_t)v*256 + off) = hq;
}

// ---------- SAGE GEMM: 128-row tiles, pure-bf16 A (global_load_lds), split W, 2 MFMAs/tile ----------
template<int KL, int NT, bool RELU>
__global__ __launch_bounds__(256) void k_gemm(
    const char* __restrict__ A1, const char* __restrict__ A2,
    const unsigned short* __restrict__ Wh, const unsigned short* __restrict__ Wl,
    const float* __restrict__ bias, char* __restrict__ Y){
  constexpr int NOUT = NT * 16;
  constexpr int KC = KL / 64;
  constexpr int NBI = NOUT / 32;
  __shared__ __align__(16) char sA [128*128];
  __shared__ __align__(16) char sBh[NOUT*128];
  __shared__ __align__(16) char sBl[NOUT*128];
  const int tid = threadIdx.x;
  const int wave = tid >> 6, lane = tid & 63;
  const int blockRow = blockIdx.x * 128;
  const int srow = lane >> 3, slot = lane & 7;
  const int sb = (slot*16) ^ (srow << 4);
  size_t aoff[4];
  #pragma unroll
  for (int i = 0; i < 4; i++){
    int grow = blockRow + wave*32 + i*8 + srow;
    if (grow >= M_NODES) grow = M_NODES - 1;
    aoff[i] = (size_t)grow*256 + sb;
  }
  size_t boff[NBI];
  #pragma unroll
  for (int i = 0; i < NBI; i++){
    int n = wave*(NOUT/4) + i*8 + srow;
    boff[i] = (size_t)n*(2*KL) + sb;
  }
  f32x4 acc[2][NT];
  #pragma unroll
  for (int a = 0; a < 2; a++)
    #pragma unroll
    for (int i = 0; i < NT; i++)
      #pragma unroll
      for (int r = 0; r < 4; r++) acc[a][i][r] = 0.f;

  for (int kc = 0; kc < KC; kc++){
    const char* Ap; int acolb;
    if (KL == 256 && kc >= 2){ Ap = A2; acolb = (kc - 2)*128; }
    else                     { Ap = A1; acolb = kc*128; }
    const int bcolb = kc*128;
    __syncthreads();
    #pragma unroll
    for (int i = 0; i < 4; i++){
      const int lr = (wave*32 + i*8)*128;
      gl_lds16(Ap + aoff[i] + acolb, sA + lr);
    }
    #pragma unroll
    for (int i = 0; i < NBI; i++){
      const int lr = (wave*(NOUT/4) + i*8)*128;
      gl_lds16(reinterpret_cast<const char*>(Wh) + boff[i] + bcolb, sBh + lr);
      gl_lds16(reinterpret_cast<const char*>(Wl) + boff[i] + bcolb, sBl + lr);
    }
    __syncthreads();
    #pragma unroll
    for (int ks = 0; ks < 2; ks++){
      const int kb = (ks*32 + ((lane >> 4) * 8)) * 2;
      bf16x8 ah[2];
      #pragma unroll
      for (int ar = 0; ar < 2; ar++){
        const int arow = wave*32 + ar*16 + (lane & 15);
        ah[ar] = *reinterpret_cast<const bf16x8*>(sA + arow*128 + (kb ^ ((arow & 7) << 4)));
      }
      #pragma unroll
      for (int nt = 0; nt < NT; nt++){
        const int n = nt*16 + (lane & 15);
        const int bb = n*128 + (kb ^ ((n & 7) << 4));
        const bf16x8 bh = *reinterpret_cast<const bf16x8*>(sBh + bb);
        const bf16x8 bl = *reinterpret_cast<const bf16x8*>(sBl + bb);
        #pragma unroll
        for (int ar = 0; ar < 2; ar++){
          acc[ar][nt] = __builtin_amdgcn_mfma_f32_16x16x32_bf16(ah[ar], bh, acc[ar][nt], 0, 0, 0);
          acc[ar][nt] = __builtin_amdgcn_mfma_f32_16x16x32_bf16(ah[ar], bl, acc[ar][nt], 0, 0, 0);
        }
      }
    }
  }
  const int r0 = (lane >> 4) * 4;
  #pragma unroll
  for (int ar = 0; ar < 2; ar++){
    const int growb = blockRow + wave*32 + ar*16 + r0;
    #pragma unroll
    for (int nt = 0; nt < NT; nt++){
      const int colx = nt*16 + (lane & 15);
      const float bsv = bias[colx];
      #pragma unroll
      for (int r = 0; r < 4; r++){
        const int grow = growb + r;
        float vv = acc[ar][nt][r] + bsv;
        if (RELU) vv = fmaxf(vv, 0.f);
        const float vo = __shfl_xor(vv, 1);
        if ((lane & 1) == 0 && grow < M_NODES){
          const unsigned hv = (unsigned)f2bf(vv) | ((unsigned)f2bf(vo) << 16);
          *reinterpret_cast<unsigned*>(Y + (size_t)grow*256 + colx*2) = hv;
        }
      }
    }
  }
}

// ---------- fused MLP: 3 layers in one kernel, intermediates in LDS ----------
__global__ __launch_bounds__(256) void k_mlp(const char* __restrict__ X,
    const unsigned short* __restrict__ L0h, const unsigned short* __restrict__ L0l,
    const unsigned short* __restrict__ L1h, const unsigned short* __restrict__ L1l,
    const unsigned short* __restrict__ L2h, const unsigned short* __restrict__ L2l,
    const float* __restrict__ b0, const float* __restrict__ b1,
    const float* __restrict__ b2, float* __restrict__ Y){
  __shared__ __align__(16) char sA [128*128];
  __shared__ __align__(16) char sBh[128*128];
  __shared__ __align__(16) char sBl[128*128];
  __shared__ __align__(16) char sX [2][128*128];
  const int tid = threadIdx.x;
  const int wave = tid >> 6, lane = tid & 63;
  const int blockRow = blockIdx.x * 128;
  const int srow = lane >> 3, slot = lane & 7;
  const int sb = (slot*16) ^ (srow << 4);
  size_t aoff[4];
  #pragma unroll
  for (int i = 0; i < 4; i++){
    int grow = blockRow + wave*32 + i*8 + srow;
    if (grow >= M_NODES) grow = M_NODES - 1;
    aoff[i] = (size_t)grow*256 + sb;
  }
  const int r0 = (lane >> 4) * 4;
  f32x4 acc[2][8];

  // ===== layer 1 =====
  #pragma unroll
  for (int a = 0; a < 2; a++)
    #pragma unroll
    for (int i = 0; i < 8; i++)
      #pragma unroll
      for (int r = 0; r < 4; r++) acc[a][i][r] = 0.f;
  for (int kc = 0; kc < 2; kc++){
    __syncthreads();
    #pragma unroll
    for (int i = 0; i < 4; i++){
      const int lr = (wave*32 + i*8)*128;
      gl_lds16(X + aoff[i] + kc*128, sA + lr);
      const size_t wo = (size_t)(wave*32 + i*8 + srow)*256 + kc*128 + sb;
      gl_lds16(reinterpret_cast<const char*>(L0h) + wo, sBh + lr);
      gl_lds16(reinterpret_cast<const char*>(L0l) + wo, sBl + lr);
    }
    __syncthreads();
    #pragma unroll
    for (int ks = 0; ks < 2; ks++){
      const int kb = (ks*32 + ((lane >> 4) * 8)) * 2;
      bf16x8 ah[2];
      #pragma unroll
      for (int ar = 0; ar < 2; ar++){
        const int arow = wave*32 + ar*16 + (lane & 15);
        ah[ar] = *reinterpret_cast<const bf16x8*>(sA + arow*128 + (kb ^ ((arow & 7) << 4)));
      }
      #pragma unroll
      for (int nt = 0; nt < 8; nt++){
        const int n = nt*16 + (lane & 15);
        const int bb = n*128 + (kb ^ ((n & 7) << 4));
        const bf16x8 bh = *reinterpret_cast<const bf16x8*>(sBh + bb);
        const bf16x8 bl = *reinterpret_cast<const bf16x8*>(sBl + bb);
        #pragma unroll
        for (int ar = 0; ar < 2; ar++){
          acc[ar][nt] = __builtin_amdgcn_mfma_f32_16x16x32_bf16(ah[ar], bh, acc[ar][nt], 0, 0, 0);
          acc[ar][nt] = __builtin_amdgcn_mfma_f32_16x16x32_bf16(ah[ar], bl, acc[ar][nt], 0, 0, 0);
        }
      }
    }
  }
  #pragma unroll
  for (int ar = 0; ar < 2; ar++){
    const int lrow0 = wave*32 + ar*16 + r0;
    #pragma unroll
    for (int nt = 0; nt < 8; nt++){
      const int colx = nt*16 + (lane & 15);
      const float bsv = b0[colx];
      #pragma unroll
      for (int r = 0; r < 4; r++){
        const int lrow = lrow0 + r;
        float vv = fmaxf(acc[ar][nt][r] + bsv, 0.f);
        const float vo = __shfl_xor(vv, 1);
        if ((lane & 1) == 0){
          const unsigned hv = (unsigned)f2bf(vv) | ((unsigned)f2bf(vo) << 16);
          const int k2 = (colx & 63)*2;
          *reinterpret_cast<unsigned*>(sX[colx >> 6] + lrow*128 + (k2 ^ ((lrow & 7) << 4))) = hv;
        }
      }
    }
  }
  // ===== layer 2 =====
  #pragma unroll
  for (int a = 0; a < 2; a++)
    #pragma unroll
    for (int i = 0; i < 8; i++)
      #pragma unroll
      for (int r = 0; r < 4; r++) acc[a][i][r] = 0.f;
  for (int kc = 0; kc < 2; kc++){
    __syncthreads();
    #pragma unroll
    for (int i = 0; i < 4; i++){
      const int lr = (wave*32 + i*8)*128;
      const size_t wo = (size_t)(wave*32 + i*8 + srow)*256 + kc*128 + sb;
      gl_lds16(reinterpret_cast<const char*>(L1h) + wo, sBh + lr);
      gl_lds16(reinterpret_cast<const char*>(L1l) + wo, sBl + lr);
    }
    __syncthreads();
    #pragma unroll
    for (int ks = 0; ks < 2; ks++){
      const int kb = (ks*32 + ((lane >> 4) * 8)) * 2;
      bf16x8 ah[2];
      #pragma unroll
      for (int ar = 0; ar < 2; ar++){
        const int arow = wave*32 + ar*16 + (lane & 15);
        ah[ar] = *reinterpret_cast<const bf16x8*>(sX[kc] + arow*128 + (kb ^ ((arow & 7) << 4)));
      }
      #pragma unroll
      for (int nt = 0; nt < 8; nt++){
        const int n = nt*16 + (lane & 15);
        const int bb = n*128 + (kb ^ ((n & 7) << 4));
        const bf16x8 bh = *reinterpret_cast<const bf16x8*>(sBh + bb);
        const bf16x8 bl = *reinterpret_cast<const bf16x8*>(sBl + bb);
        #pragma unroll
        for (int ar = 0; ar < 2; ar++){
          acc[ar][nt] = __builtin_amdgcn_mfma_f32_16x16x32_bf16(ah[ar], bh, acc[ar][nt], 0, 0, 0);
          acc[ar][nt] = __builtin_amdgcn_mfma_f32_16x16x32_bf16(ah[ar], bl, acc[ar][nt], 0, 0, 0);
        }
      }
    }
  }
  __syncthreads();
  #pragma unroll
  for (int ar = 0; ar < 2; ar++){
    const int lrow0 = wave*32 + ar*16 + r0;
    #pragma unroll
    for (int nt = 0; nt < 8; nt++){
      const int colx = nt*16 + (lane & 15);
      const float bsv = b1[colx];
      #pragma unroll
      for (int r = 0; r < 4; r++){
        const int lrow = lrow0 + r;
        float vv = fmaxf(acc[ar][nt][r] + bsv, 0.f);
        const float vo = __shfl_xor(vv, 1);
        if ((lane & 1) == 0){
          const unsigned hv = (unsigned)f2bf(vv) | ((unsigned)f2bf(vo) << 16);
          const int k2 = (colx & 63)*2;
          *reinterpret_cast<unsigned*>(sX[colx >> 6] + lrow*128 + (k2 ^ ((lrow & 7) << 4))) = hv;
        }
      }
    }
  }
  // ===== layer 3 =====
  #pragma unroll
  for (int a = 0; a < 2; a++)
    #pragma unroll
    for (int i = 0; i < 4; i++)
      #pragma unroll
      for (int r = 0; r < 4; r++) acc[a][i][r] = 0.f;
  for (int kc = 0; kc < 2; kc++){
    __syncthreads();
    #pragma unroll
    for (int i = 0; i < 2; i++){
      const int lr = (wave*16 + i*8)*128;
      const size_t wo = (size_t)(wave*16 + i*8 + srow)*256 + kc*128 + sb;
      gl_lds16(reinterpret_cast<const char*>(L2h) + wo, sBh + lr);
      gl_lds16(reinterpret_cast<const char*>(L2l) + wo, sBl + lr);
    }
    __syncthreads();
    #pragma unroll
    for (int ks = 0; ks < 2; ks++){
      const int kb = (ks*32 + ((lane >> 4) * 8)) * 2;
      bf16x8 ah[2];
      #pragma unroll
      for (int ar = 0; ar < 2; ar++){
        const int arow = wave*32 + ar*16 + (lane & 15);
        ah[ar] = *reinterpret_cast<const bf16x8*>(sX[kc] + arow*128 + (kb ^ ((arow & 7) << 4)));
      }
      #pragma unroll
      for (int nt = 0; nt < 4; nt++){
        const int n = nt*16 + (lane & 15);
        const int bb = n*128 + (kb ^ ((n & 7) << 4));
        const bf16x8 bh = *reinterpret_cast<const bf16x8*>(sBh + bb);
        const bf16x8 bl = *reinterpret_cast<const bf16x8*>(sBl + bb);
        #pragma unroll
        for (int ar = 0; ar < 2; ar++){
          acc[ar][nt] = __builtin_amdgcn_mfma_f32_16x16x32_bf16(ah[ar], bh, acc[ar][nt], 0, 0, 0);
          acc[ar][nt] = __builtin_amdgcn_mfma_f32_16x16x32_bf16(ah[ar], bl, acc[ar][nt], 0, 0, 0);
        }
      }
    }
  }
  #pragma unroll
  for (int ar = 0; ar < 2; ar++){
    const int growb = blockRow + wave*32 + ar*16 + r0;
    #pragma unroll
    for (int nt = 0; nt < 4; nt++){
      const int colx = nt*16 + (lane & 15);
      const float bsv = b2[colx];
      #pragma unroll
      for (int r = 0; r < 4; r++){
        const int grow = growb + r;
        if (grow < M_NODES)
          Y[(size_t)grow*64 + colx] = acc[ar][nt][r] + bsv;
      }
    }
  }
}

// ---------- pooling stage 1: 8 sub-chunks per graph ----------
__global__ __launch_bounds__(256) void k_pool1(const float* __restrict__ Xf,
    const int* __restrict__ gcnt, float* __restrict__ pp){
  const int g = blockIdx.x >> 3, s = blockIdx.x & 7;
  const int tid = threadIdx.x, w = tid >> 6, lane = tid & 63;
  __shared__ int sstart;
  __shared__ float part[4][64];
  if (w == 0){
    int v = gcnt[lane];
    int x = v;
    #pragma unroll
    for (int off = 1; off < 64; off <<= 1){
      int y = __shfl_up(x, off);
      if (lane >= off) x += y;
    }
    if (lane == g) sstart = x - v;
  }
  __syncthreads();
  const int cg = gcnt[g];
  const int Lc = (cg + 7) >> 3;
  const int nbeg = sstart + s*Lc;
  const int nend = min(nbeg + Lc, sstart + cg);
  float a0 = 0.f, a1 = 0.f;
  int i = nbeg + w;
  for (; i + 4 < nend; i += 8){
    a0 += Xf[(size_t)i*64 + lane];
    a1 += Xf[(size_t)(i+4)*64 + lane];
  }
  if (i < nend) a0 += Xf[(size_t)i*64 + lane];
  part[w][lane] = a0 + a1;
  __syncthreads();
  if (w == 0)
    pp[(size_t)(g*8 + s)*64 + lane] = part[0][lane] + part[1][lane] + part[2][lane] + part[3][lane];
}

// ---------- pooling stage 2 ----------
__global__ __launch_bounds__(64) void k_pool2(const float* __restrict__ pp,
    const int* __restrict__ gcnt, float* __restrict__ out){
  const int g = blockIdx.x, lane = threadIdx.x;
  float sum = 0.f;
  #pragma unroll
  for (int s = 0; s < 8; s++) sum += pp[(size_t)(g*8 + s)*64 + lane];
  out[g*64 + lane] = sum / fmaxf((float)gcnt[g], 1.f);
}

extern "C" void kernel_launch(void* const* d_in, const int* in_sizes, int n_in,
                              void* d_out, int out_size, void* d_ws, size_t ws_size,
                              hipStream_t stream){
  const float* h    = (const float*)d_in[0];
  const int*   esrc = (const int*)d_in[1];
  const int*   edst = (const int*)d_in[2];
  const int*   gid  = (const int*)d_in[3];
  const float* ws0  = (const float*)d_in[4];
  const float* wn0  = (const float*)d_in[5];
  const float* bs0  = (const float*)d_in[6];
  const float* ws1  = (const float*)d_in[7];
  const float* wn1  = (const float*)d_in[8];
  const float* bs1  = (const float*)d_in[9];
  const float* ws2  = (const float*)d_in[10];
  const float* wn2  = (const float*)d_in[11];
  const float* bs2  = (const float*)d_in[12];
  const float* lw0  = (const float*)d_in[13];
  const float* lb0  = (const float*)d_in[14];
  const float* lw1  = (const float*)d_in[15];
  const float* lb1  = (const float*)d_in[16];
  const float* lw2  = (const float*)d_in[17];
  const float* lb2  = (const float*)d_in[18];
  float* out = (float*)d_out;

  char* p = (char*)d_ws;
  auto alloc = [&](size_t b)->char*{ char* r = p; p += (b + 255) & ~(size_t)255; return r; };
  char* X0 = alloc((size_t)M_NODES*256);
  char* XA = alloc((size_t)M_NODES*256);
  char* XB = alloc((size_t)M_NODES*256);
  char* G  = alloc((size_t)M_NODES*256);
  float* xF = (float*)alloc((size_t)M_NODES*64*4);
  float* pp = (float*)alloc((size_t)64*8*64*4);
  char* zbase = p;
  int* gcnt  = (int*)alloc(256);
  size_t zbytes = (size_t)(p - zbase);
  unsigned* part = (unsigned*)alloc((size_t)B_H*HWORDS*4);
  int* cbase = (int*)alloc((size_t)B_H*M_NODES*4);
  int* rp    = (int*)alloc((size_t)(M_NODES+1)*4);
  int* col   = (int*)alloc((size_t)E_EDGES*4);
  int* bsum  = (int*)alloc((size_t)SCAN_B*4);
  unsigned short* W0h = (unsigned short*)alloc(128*256*2);
  unsigned short* W0l = (unsigned short*)alloc(128*256*2);
  unsigned short* W1h = (unsigned short*)alloc(128*256*2);
  unsigned short* W1l = (unsigned short*)alloc(128*256*2);
  unsigned short* W2h = (unsigned short*)alloc(128*256*2);
  unsigned short* W2l = (unsigned short*)alloc(128*256*2);
  unsigned short* L0h = (unsigned short*)alloc(128*128*2);
  unsigned short* L0l = (unsigned short*)alloc(128*128*2);
  unsigned short* L1h = (unsigned short*)alloc(128*128*2);
  unsigned short* L1l = (unsigned short*)alloc(128*128*2);
  unsigned short* L2h = (unsigned short*)alloc(64*128*2);
  unsigned short* L2l = (unsigned short*)alloc(64*128*2);

  hipMemsetAsync(zbase, 0, zbytes, stream);
  k_prep<<<544 + (M_NODES*16 + 255)/256, 256, 0, stream>>>(
      ws0, wn0, ws1, wn1, ws2, wn2, lw0, lw1, lw2, h,
      W0h, W0l, W1h, W1l, W2h, W2l, L0h, L0l, L1h, L1l, L2h, L2l, X0);
  k_hist<<<B_H, 256, HWORDS*4, stream>>>(edst, part);
  k_scan1<<<SCAN_B, 256, 0, stream>>>(part, rp, bsum);
  k_cbase<<<SCAN_B, 256, 0, stream>>>(rp, bsum, part, cbase, gid, gcnt);
  k_fill<<<B_H, 256, HWORDS*4, stream>>>(esrc, edst, cbase, col);

  const int gGrid = (M_NODES + 127)/128;
  const int aGrid = (M_NODES + 15)/16;
  // SAGE layer 0 (relu)
  k_agg<<<aGrid, 256, 0, stream>>>(X0, rp, col, G);
  k_gemm<256,8,true ><<<gGrid,256,0,stream>>>(X0, G, W0h, W0l, bs0, XA);
  // SAGE layer 1 (relu)
  k_agg<<<aGrid, 256, 0, stream>>>(XA, rp, col, G);
  k_gemm<256,8,true ><<<gGrid,256,0,stream>>>(XA, G, W1h, W1l, bs1, XB);
  // SAGE layer 2 (no relu)
  k_agg<<<aGrid, 256, 0, stream>>>(XB, rp, col, G);
  k_gemm<256,8,false><<<gGrid,256,0,stream>>>(XB, G, W2h, W2l, bs2, XA);
  // fused MLP (3 layers)
  k_mlp<<<gGrid, 256, 0, stream>>>(XA, L0h, L0l, L1h, L1l, L2h, L2l, lb0, lb1, lb2, xF);
  // pooling
  k_pool1<<<512, 256, 0, stream>>>(xF, gcnt, pp);
  k_pool2<<<64, 64, 0, stream>>>(pp, gcnt, out);
}